// Round 11
// baseline (305.066 us; speedup 1.0000x reference)
//
#include <hip/hip_runtime.h>
#include <hip/hip_bf16.h>

typedef __attribute__((ext_vector_type(8))) short short8;
typedef __attribute__((ext_vector_type(8))) _Float16 half8;
typedef __attribute__((ext_vector_type(4))) float f32x4;

__device__ __forceinline__ unsigned short f2h(float f) {
    _Float16 h = (_Float16)f;
    return *reinterpret_cast<unsigned short*>(&h);
}
__device__ __forceinline__ float h2f(unsigned short u) {
    _Float16 h = *reinterpret_cast<_Float16*>(&u);
    return (float)h;
}

// async global->LDS, 16B per lane, wave-uniform LDS base + lane*16 dest
__device__ __forceinline__ void gld_lds16(const unsigned short* g, unsigned short* l) {
    __builtin_amdgcn_global_load_lds(
        (const __attribute__((address_space(1))) unsigned int*)g,
        (__attribute__((address_space(3))) unsigned int*)l, 16, 0, 0);
}

// ---------------- fused weight transpose + fp16 convert (one launch) ----------------
__global__ __launch_bounds__(256)
void transpose_all(const float* __restrict__ W0, const float* __restrict__ W1,
                   const float* __restrict__ W2, const float* __restrict__ W3,
                   unsigned short* __restrict__ o0, unsigned short* __restrict__ o1,
                   unsigned short* __restrict__ o2, unsigned short* __restrict__ o3) {
    __shared__ float tile[32][33];
    const int bid = blockIdx.x;
    const float* W; unsigned short* out; int K, N, loc;
    if (bid < 3072)      { W = W0; out = o0; K = 1024; N = 3072; loc = bid; }
    else if (bid < 4096) { W = W1; out = o1; K = 1024; N = 1024; loc = bid - 3072; }
    else if (bid < 8192) { W = W2; out = o2; K = 1024; N = 4096; loc = bid - 4096; }
    else                 { W = W3; out = o3; K = 4096; N = 1024; loc = bid - 8192; }
    const int nx = N >> 5;
    const int n0 = (loc % nx) << 5, k0 = (loc / nx) << 5;
    const int tid = threadIdx.x;
    const int r = tid >> 3, c4 = (tid & 7) << 2;
    float4 v = *reinterpret_cast<const float4*>(W + (size_t)(k0 + r) * N + n0 + c4);
    tile[r][c4 + 0] = v.x; tile[r][c4 + 1] = v.y;
    tile[r][c4 + 2] = v.z; tile[r][c4 + 3] = v.w;
    __syncthreads();
    const int n = n0 + r;
    ushort4 o;
    o.x = f2h(tile[c4 + 0][r]); o.y = f2h(tile[c4 + 1][r]);
    o.z = f2h(tile[c4 + 2][r]); o.w = f2h(tile[c4 + 3][r]);
    *reinterpret_cast<ushort4*>(out + (size_t)n * K + k0 + c4) = o;
}

// ---------------- LayerNorm -> fp16 [row][1024] ----------------
__global__ __launch_bounds__(256)
void ln_kernel(const float* __restrict__ x, const float* __restrict__ gw,
               const float* __restrict__ bw, unsigned short* __restrict__ out) {
    const int row = blockIdx.x, tid = threadIdx.x;
    const float* xr = x + (size_t)row * 1024;
    float4 v = *reinterpret_cast<const float4*>(xr + tid * 4);
    float s = v.x + v.y + v.z + v.w;
    float sq = v.x * v.x + v.y * v.y + v.z * v.z + v.w * v.w;
    #pragma unroll
    for (int off = 1; off < 64; off <<= 1) {
        s  += __shfl_xor(s, off);
        sq += __shfl_xor(sq, off);
    }
    __shared__ float ps[4], pq[4];
    const int wave = tid >> 6;
    if ((tid & 63) == 0) { ps[wave] = s; pq[wave] = sq; }
    __syncthreads();
    s  = ps[0] + ps[1] + ps[2] + ps[3];
    sq = pq[0] + pq[1] + pq[2] + pq[3];
    const float mu = s * (1.0f / 1024.0f);
    const float var = sq * (1.0f / 1024.0f) - mu * mu;
    const float rs = rsqrtf(var + 1e-5f);
    float4 gv = *reinterpret_cast<const float4*>(gw + tid * 4);
    float4 bv = *reinterpret_cast<const float4*>(bw + tid * 4);
    ushort4 o;
    o.x = f2h((v.x - mu) * rs * gv.x + bv.x);
    o.y = f2h((v.y - mu) * rs * gv.y + bv.y);
    o.z = f2h((v.z - mu) * rs * gv.z + bv.z);
    o.w = f2h((v.w - mu) * rs * gv.w + bv.w);
    *reinterpret_cast<ushort4*>(out + (size_t)row * 1024 + tid * 4) = o;
}

// ---------------- big-tile GEMM: 128x256, BK=64, 8 waves (2Mx4N) --------------------
// Ring of 3 LDS buffers (144KB), prefetch depth 2, counted vmcnt (T3/T4):
//   steady state: vmcnt(6) at each tile boundary keeps the next tile's 6 loads
//   (per wave: A x2 + B x4) in flight across the barrier; never drains to 0 except
//   at the last tile. stage(t+2) is issued AFTER the barrier (WAR-safe: buffer
//   (t+2)%3's last readers finished at iteration t-1).
// LDS chunk-swizzle (rule 21): linear DMA dest + inverse-swizzled global SOURCE +
// swizzled ds_read: phys_chunk(16B) = logical_chunk ^ (row & 7) -> 2-way (free).
// EPI 0: fp16 = acc+bias ; EPI 2: fp16 = gelu(acc+bias)
template<int EPI>
__global__ __launch_bounds__(512, 2)
void gemm256(const unsigned short* __restrict__ A, const unsigned short* __restrict__ Bt,
             const float* __restrict__ bias, void* Cout,
             int M, int N, int K, int lda, int ldb, int ldc) {
    __shared__ unsigned short As[3][128 * 64];   // 16KB per buf
    __shared__ unsigned short Bs[3][256 * 64];   // 32KB per buf  (total 144KB)
    const int tid = threadIdx.x;
    const int wave = tid >> 6, lane = tid & 63;
    // bijective XCD swizzle (gridDim.x % 8 == 0 for our shapes)
    const int nwg = gridDim.x;
    const int swz = (blockIdx.x & 7) * (nwg >> 3) + (blockIdx.x >> 3);
    const int nx = N >> 8;
    const int bm = (swz / nx) << 7, bn = (swz % nx) << 8;
    const int wm = wave >> 2, wn = wave & 3;     // 2 M-waves x 4 N-waves, 64x64 each
    const int fr = lane & 15, g8 = (lane >> 4) << 3, fq = (lane >> 4) << 2;
    const int jq = g8 >> 3;          // logical chunk within 32-col k-step (0..3)
    const int sx = fr & 7;           // read-side row XOR (row bases are %8==0)

    // staging: A rows wave*16..+15 (2 issues of 8 rows), B rows wave*32..+31 (4 issues).
    // per 1KB issue: lane l -> LDS row base+(l>>3), phys chunk l&7 => global source
    // logical chunk (l&7)^(l>>3) of row base+(l>>3)  (base % 8 == 0).
    const int srow = lane >> 3;
    const int scol = ((lane & 7) ^ srow) << 3;
    const unsigned short* gA = A + (size_t)(bm + wave * 16 + srow) * lda + scol;
    const unsigned short* gB = Bt + (size_t)(bn + wave * 32 + srow) * ldb + scol;
    const int lbA = wave * 16 * 64;   // wave-uniform LDS bases (shorts)
    const int lbB = wave * 32 * 64;

    f32x4 acc[4][4];
    #pragma unroll
    for (int m = 0; m < 4; ++m)
        #pragma unroll
        for (int n_ = 0; n_ < 4; ++n_)
            #pragma unroll
            for (int r_ = 0; r_ < 4; ++r_) acc[m][n_][r_] = 0.0f;

    auto stage = [&](int buf, int k0) {
        gld_lds16(gA + k0, &As[buf][lbA]);
        gld_lds16(gA + (size_t)8 * lda + k0, &As[buf][lbA + 512]);
        #pragma unroll
        for (int i = 0; i < 4; ++i)
            gld_lds16(gB + (size_t)(i * 8) * ldb + k0, &Bs[buf][lbB + i * 512]);
    };
    auto compute = [&](int buf) {
        half8 av[4][2], bv[4][2];
        #pragma unroll
        for (int n_ = 0; n_ < 4; ++n_) {
            const int rb = (wn * 64 + n_ * 16 + fr) * 64;
            #pragma unroll
            for (int kk = 0; kk < 2; ++kk)
                bv[n_][kk] = *reinterpret_cast<const half8*>(
                    &Bs[buf][rb + (((kk * 4 + jq) ^ sx) << 3)]);
        }
        #pragma unroll
        for (int m = 0; m < 4; ++m) {
            const int rb = (wm * 64 + m * 16 + fr) * 64;
            #pragma unroll
            for (int kk = 0; kk < 2; ++kk)
                av[m][kk] = *reinterpret_cast<const half8*>(
                    &As[buf][rb + (((kk * 4 + jq) ^ sx) << 3)]);
        }
        #pragma unroll
        for (int kk = 0; kk < 2; ++kk)
            #pragma unroll
            for (int m = 0; m < 4; ++m)
                #pragma unroll
                for (int n_ = 0; n_ < 4; ++n_)
                    acc[m][n_] = __builtin_amdgcn_mfma_f32_16x16x32_f16(
                        av[m][kk], bv[n_][kk], acc[m][n_], 0, 0, 0);
    };

    const int NT = K >> 6;              // >= 2 for all our shapes
    stage(0, 0);
    stage(1, 64);
    for (int t = 0; t < NT - 1; ++t) {
        asm volatile("s_waitcnt vmcnt(6)" ::: "memory");   // tile t landed; t+1 in flight
        __builtin_amdgcn_s_barrier();
        __builtin_amdgcn_sched_barrier(0);
        if (t + 2 < NT) stage((t + 2) % 3, (t + 2) << 6);
        compute(t % 3);
    }
    asm volatile("s_waitcnt vmcnt(0)" ::: "memory");       // last tile
    __builtin_amdgcn_s_barrier();
    __builtin_amdgcn_sched_barrier(0);
    compute((NT - 1) % 3);

    unsigned short* o16 = reinterpret_cast<unsigned short*>(Cout);
    #pragma unroll
    for (int n_ = 0; n_ < 4; ++n_) {
        const int col = bn + wn * 64 + n_ * 16 + fr;
        const float bc = bias[col];
        #pragma unroll
        for (int m = 0; m < 4; ++m) {
            #pragma unroll
            for (int r_ = 0; r_ < 4; ++r_) {
                const int row = bm + wm * 64 + m * 16 + fq + r_;
                const size_t idx = (size_t)row * ldc + col;
                float v = acc[m][n_][r_] + bc;
                if (EPI == 0) {
                    o16[idx] = f2h(v);
                } else {
                    float ge = 0.5f * v * (1.0f + erff(v * 0.70710678118654752f));
                    o16[idx] = f2h(ge);
                }
            }
        }
    }
}

// ---------------- 2-phase GEMM (skinny shapes), BK=32 chunk-swizzle -----------------
// EPI 1: f32 = acc+bias+resid ; EPI 3: raw f32 partial (split-K over blockIdx.z)
template<int EPI, int BM>
__global__ __launch_bounds__(256)
void gemm_bt(const unsigned short* __restrict__ A, const unsigned short* __restrict__ Bt,
             const float* __restrict__ bias, const float* resid,
             void* Cout, int M, int N, int K, int lda, int ldb, int ldc) {
    constexpr int MF = BM / 32;
    __shared__ unsigned short As[2][BM * 32];
    __shared__ unsigned short Bs[2][128 * 32];
    const int tid = threadIdx.x;
    const int wave = tid >> 6, lane = tid & 63;
    const int bm = blockIdx.y * BM, bn = blockIdx.x << 7;
    const int wr = (wave >> 1) * (BM / 2), wc = (wave & 1) << 6;
    const int fr = lane & 15, g8 = (lane >> 4) << 3, fq = (lane >> 4) << 2;
    const int jq = g8 >> 3, sx2 = (fr >> 1) & 3;
    const size_t koff = (EPI == 3) ? (size_t)blockIdx.z * K : 0;

    const int srowA = (BM == 128) ? ((wave << 5) + (lane >> 2)) : ((wave << 4) + (lane >> 2));
    const int srowB = (wave << 5) + (lane >> 2);
    const int scol = (((lane & 3) ^ ((lane >> 3) & 3))) << 3;
    const unsigned short* gA0 = A + (size_t)(bm + srowA) * lda + scol + koff;
    const unsigned short* gA1 = gA0 + (size_t)16 * lda;      // BM==128 only
    const unsigned short* gB0 = Bt + (size_t)(bn + srowB) * ldb + scol + koff;
    const unsigned short* gB1 = gB0 + (size_t)16 * ldb;

    f32x4 acc[MF][4];
    #pragma unroll
    for (int m = 0; m < MF; ++m)
        #pragma unroll
        for (int n = 0; n < 4; ++n)
            #pragma unroll
            for (int r = 0; r < 4; ++r) acc[m][n][r] = 0.0f;

    auto stage = [&](int buf, int k0) {
        unsigned short* lA = &As[buf][(BM == 128) ? (wave << 10) : (wave << 9)];
        unsigned short* lB = &Bs[buf][wave << 10];
        gld_lds16(gA0 + k0, lA);
        if constexpr (BM == 128) gld_lds16(gA1 + k0, lA + 512);
        gld_lds16(gB0 + k0, lB);
        gld_lds16(gB1 + k0, lB + 512);
    };
    auto compute = [&](int buf) {
        half8 af[MF], bfv[4];
        #pragma unroll
        for (int m = 0; m < MF; ++m)
            af[m] = *reinterpret_cast<const half8*>(
                &As[buf][(wr + m * 16 + fr) * 32 + ((jq ^ sx2) << 3)]);
        #pragma unroll
        for (int n = 0; n < 4; ++n)
            bfv[n] = *reinterpret_cast<const half8*>(
                &Bs[buf][(wc + n * 16 + fr) * 32 + ((jq ^ sx2) << 3)]);
        #pragma unroll
        for (int m = 0; m < MF; ++m)
            #pragma unroll
            for (int n = 0; n < 4; ++n)
                acc[m][n] = __builtin_amdgcn_mfma_f32_16x16x32_f16(af[m], bfv[n], acc[m][n], 0, 0, 0);
    };

    const int nt = K >> 5;
    stage(0, 0);
    __syncthreads();
    int k0 = 32;
    for (int t = 0; t < nt - 2; t += 2) {
        stage(1, k0);
        compute(0);
        __syncthreads();
        stage(0, k0 + 32);
        compute(1);
        __syncthreads();
        k0 += 64;
    }
    stage(1, k0);
    compute(0);
    __syncthreads();
    compute(1);

    if (EPI == 3) {
        float* P = reinterpret_cast<float*>(Cout) + (size_t)blockIdx.z * (size_t)M * ldc;
        #pragma unroll
        for (int n = 0; n < 4; ++n) {
            const int col = bn + wc + n * 16 + fr;
            #pragma unroll
            for (int m = 0; m < MF; ++m)
                #pragma unroll
                for (int r = 0; r < 4; ++r) {
                    const int row = bm + wr + m * 16 + fq + r;
                    P[(size_t)row * ldc + col] = acc[m][n][r];
                }
        }
        return;
    }

    #pragma unroll
    for (int n = 0; n < 4; ++n) {
        const int col = bn + wc + n * 16 + fr;
        const float bc = bias[col];
        #pragma unroll
        for (int m = 0; m < MF; ++m) {
            #pragma unroll
            for (int r = 0; r < 4; ++r) {
                const int row = bm + wr + m * 16 + fq + r;
                const size_t idx = (size_t)row * ldc + col;
                float v = acc[m][n][r] + bc;
                reinterpret_cast<float*>(Cout)[idx] = v + resid[idx];   // EPI 1
            }
        }
    }
}

// ---------------- split-K reduce (fc2): out = out + bias + sum_z p[z] ----------------
template<int Z>
__global__ __launch_bounds__(256)
void red_kernel(const float* __restrict__ p, const float* __restrict__ bias,
                float* out) {
    const size_t MN = (size_t)4096 * 1024;
    const size_t i = ((size_t)blockIdx.x * 256 + threadIdx.x) * 4;
    float4 r  = *reinterpret_cast<const float4*>(out + i);
    float4 bb = *reinterpret_cast<const float4*>(bias + (i & 1023));
    float o0 = r.x + bb.x, o1 = r.y + bb.y, o2 = r.z + bb.z, o3 = r.w + bb.w;
    #pragma unroll
    for (int z = 0; z < Z; ++z) {
        float4 a = *reinterpret_cast<const float4*>(p + (size_t)z * MN + i);
        o0 += a.x; o1 += a.y; o2 += a.z; o3 += a.w;
    }
    float4 o; o.x = o0; o.y = o1; o.z = o2; o.w = o3;
    *reinterpret_cast<float4*>(out + i) = o;
}

// ---------------- K/V compaction ----------------
__global__ __launch_bounds__(256)
void kv_conv(const unsigned short* __restrict__ qkv16, unsigned short* __restrict__ K_g,
             unsigned short* __restrict__ Vt_g) {
    __shared__ unsigned short VtT[64][72];
    const int kc = blockIdx.x;
    const int bh = blockIdx.y;
    const int b = bh >> 4, h = bh & 15;
    const int tid = threadIdx.x;
    const int key = tid >> 2, c16 = (tid & 3) << 4;
    const unsigned short* kp = qkv16 + ((size_t)(b * 1024 + kc * 64 + key)) * 3072 + 1024 + h * 64 + c16;
    alignas(16) unsigned short kbuf[16];
    #pragma unroll
    for (int j = 0; j < 16; j += 8) {
        short8 k8 = *reinterpret_cast<const short8*>(kp + j);
        short8 v8 = *reinterpret_cast<const short8*>(kp + 1024 + j);
        #pragma unroll
        for (int c = 0; c < 8; ++c) {
            kbuf[j + c] = f2h(8.0f * h2f((unsigned short)k8[c]));
            VtT[c16 + j + c][key] = (unsigned short)v8[c];
        }
    }
    const size_t kb = ((size_t)bh * 1024 + kc * 64 + key) * 64 + c16;
    *reinterpret_cast<short8*>(K_g + kb)     = *reinterpret_cast<short8*>(&kbuf[0]);
    *reinterpret_cast<short8*>(K_g + kb + 8) = *reinterpret_cast<short8*>(&kbuf[8]);
    __syncthreads();
    const int d = tid >> 2;
    const size_t vb = ((size_t)bh * 64 + d) * 1024 + (size_t)kc * 64 + c16;
    *reinterpret_cast<short8*>(Vt_g + vb)     = *reinterpret_cast<const short8*>(&VtT[d][c16]);
    *reinterpret_cast<short8*>(Vt_g + vb + 8) = *reinterpret_cast<const short8*>(&VtT[d][c16 + 8]);
}

// ---------------- Flash attention (fp16, QBLK=64, T14 register prefetch) ----------------
__global__ __launch_bounds__(256)
void attn_kernel(const unsigned short* __restrict__ qkv16,
                 const unsigned short* __restrict__ K_g,
                 const unsigned short* __restrict__ Vt_g,
                 unsigned short* __restrict__ ctx) {
    __shared__ unsigned short Kh[64][72];
    __shared__ unsigned short Vt[64][72];
    __shared__ unsigned short Plds[4][16][72];
    const int qt = blockIdx.x;
    const int bh = blockIdx.y;
    const int b = bh >> 4, h = bh & 15;
    const int tid = threadIdx.x;
    const int wave = tid >> 6, lane = tid & 63;
    const int fr = lane & 15, g8 = (lane >> 4) << 3, fq = (lane >> 4) << 2;

    const int qrow = qt * 64 + wave * 16 + fr;
    const unsigned short* qp = qkv16 + ((size_t)(b * 1024 + qrow)) * 3072 + h * 64;
    half8 qf[2];
    qf[0] = *reinterpret_cast<const half8*>(qp + g8);
    qf[1] = *reinterpret_cast<const half8*>(qp + 32 + g8);

    float mrun[4], lrun[4];
    f32x4 cacc[4];
    #pragma unroll
    for (int r = 0; r < 4; ++r) { mrun[r] = -3.0e38f; lrun[r] = 0.0f; }
    #pragma unroll
    for (int nd = 0; nd < 4; ++nd)
        #pragma unroll
        for (int r = 0; r < 4; ++r) cacc[nd][r] = 0.0f;

    const int skey = tid >> 2, sc16 = (tid & 3) << 4;
    const unsigned short* kgp = K_g + ((size_t)bh * 1024 + skey) * 64 + sc16;
    const unsigned short* vgp = Vt_g + ((size_t)bh * 64 + skey) * 1024 + sc16;

    short8 ka = *reinterpret_cast<const short8*>(kgp);
    short8 kb = *reinterpret_cast<const short8*>(kgp + 8);
    short8 va = *reinterpret_cast<const short8*>(vgp);
    short8 vb = *reinterpret_cast<const short8*>(vgp + 8);

    for (int kt = 0; kt < 16; ++kt) {
        __syncthreads();
        *reinterpret_cast<short8*>(&Kh[skey][sc16])     = ka;
        *reinterpret_cast<short8*>(&Kh[skey][sc16 + 8]) = kb;
        *reinterpret_cast<short8*>(&Vt[skey][sc16])     = va;
        *reinterpret_cast<short8*>(&Vt[skey][sc16 + 8]) = vb;
        __syncthreads();
        const int ktn = (kt < 15) ? kt + 1 : 15;
        ka = *reinterpret_cast<const short8*>(kgp + (size_t)ktn * 4096);
        kb = *reinterpret_cast<const short8*>(kgp + (size_t)ktn * 4096 + 8);
        va = *reinterpret_cast<const short8*>(vgp + ktn * 64);
        vb = *reinterpret_cast<const short8*>(vgp + ktn * 64 + 8);

        f32x4 S[4];
        #pragma unroll
        for (int n = 0; n < 4; ++n)
            #pragma unroll
            for (int r = 0; r < 4; ++r) S[n][r] = 0.0f;
        #pragma unroll
        for (int s_ = 0; s_ < 2; ++s_)
            #pragma unroll
            for (int n = 0; n < 4; ++n) {
                half8 kh = *reinterpret_cast<const half8*>(&Kh[n * 16 + fr][s_ * 32 + g8]);
                S[n] = __builtin_amdgcn_mfma_f32_16x16x32_f16(qf[s_], kh, S[n], 0, 0, 0);
            }

        float mt[4];
        #pragma unroll
        for (int r = 0; r < 4; ++r)
            mt[r] = fmaxf(fmaxf(S[0][r], S[1][r]), fmaxf(S[2][r], S[3][r]));
        #pragma unroll
        for (int r = 0; r < 4; ++r) {
            mt[r] = fmaxf(mt[r], __shfl_xor(mt[r], 1));
            mt[r] = fmaxf(mt[r], __shfl_xor(mt[r], 2));
            mt[r] = fmaxf(mt[r], __shfl_xor(mt[r], 4));
            mt[r] = fmaxf(mt[r], __shfl_xor(mt[r], 8));
        }
        float P[4][4], rsum[4];
        #pragma unroll
        for (int r = 0; r < 4; ++r) {
            float mnew = fmaxf(mrun[r], mt[r]);
            float sf = __expf(mrun[r] - mnew);
            mrun[r] = mnew;
            rsum[r] = 0.0f;
            #pragma unroll
            for (int n = 0; n < 4; ++n) {
                float p = __expf(S[n][r] - mnew);
                P[n][r] = p;
                rsum[r] += p;
            }
            lrun[r] *= sf;
            #pragma unroll
            for (int nd = 0; nd < 4; ++nd) cacc[nd][r] *= sf;
        }
        #pragma unroll
        for (int r = 0; r < 4; ++r) {
            rsum[r] += __shfl_xor(rsum[r], 1);
            rsum[r] += __shfl_xor(rsum[r], 2);
            rsum[r] += __shfl_xor(rsum[r], 4);
            rsum[r] += __shfl_xor(rsum[r], 8);
            lrun[r] += rsum[r];
        }
        #pragma unroll
        for (int n = 0; n < 4; ++n)
            #pragma unroll
            for (int r = 0; r < 4; ++r)
                Plds[wave][fq + r][n * 16 + fr] = f2h(P[n][r]);
        #pragma unroll
        for (int s_ = 0; s_ < 2; ++s_) {
            half8 pa = *reinterpret_cast<const half8*>(&Plds[wave][fr][s_ * 32 + g8]);
            #pragma unroll
            for (int nd = 0; nd < 4; ++nd) {
                half8 vb8 = *reinterpret_cast<const half8*>(&Vt[nd * 16 + fr][s_ * 32 + g8]);
                cacc[nd] = __builtin_amdgcn_mfma_f32_16x16x32_f16(pa, vb8, cacc[nd], 0, 0, 0);
            }
        }
    }
    #pragma unroll
    for (int r = 0; r < 4; ++r) {
        const float inv = 1.0f / lrun[r];
        const int row = qt * 64 + wave * 16 + fq + r;
        unsigned short* cp = ctx + ((size_t)(b * 1024 + row)) * 1024 + h * 64;
        #pragma unroll
        for (int nd = 0; nd < 4; ++nd)
            cp[nd * 16 + fr] = f2h(cacc[nd][r] * inv);
    }
}

// ---------------- launch ----------------
extern "C" void kernel_launch(void* const* d_in, const int* in_sizes, int n_in,
                              void* d_out, int out_size, void* d_ws, size_t ws_size,
                              hipStream_t stream) {
    const float* x      = (const float*)d_in[0];
    const float* norm_g = (const float*)d_in[1];
    const float* norm_b = (const float*)d_in[2];
    const float* w_qkv  = (const float*)d_in[3];
    const float* b_qkv  = (const float*)d_in[4];
    const float* w_proj = (const float*)d_in[5];
    const float* b_proj = (const float*)d_in[6];
    const float* w_fc1  = (const float*)d_in[7];
    const float* b_fc1  = (const float*)d_in[8];
    const float* w_fc2  = (const float*)d_in[9];
    const float* b_fc2  = (const float*)d_in[10];
    float* out = (float*)d_out;
    char* ws = (char*)d_ws;

    size_t off = 0;
    unsigned short* wqkvT  = (unsigned short*)(ws + off); off += (size_t)3072 * 1024 * 2;
    unsigned short* wprojT = (unsigned short*)(ws + off); off += (size_t)1024 * 1024 * 2;
    unsigned short* wfc1T  = (unsigned short*)(ws + off); off += (size_t)4096 * 1024 * 2;
    unsigned short* wfc2T  = (unsigned short*)(ws + off); off += (size_t)1024 * 4096 * 2;
    unsigned short* ctxb   = (unsigned short*)(ws + off); off += (size_t)4096 * 1024 * 2;
    char* G = ws + off;
    unsigned short* h1    = (unsigned short*)G;
    unsigned short* qkv16 = (unsigned short*)(G + (size_t)8388608);
    unsigned short* K_g   = (unsigned short*)G;
    unsigned short* Vt_g  = (unsigned short*)(G + (size_t)33554432);
    unsigned short* fc1o  = (unsigned short*)G;
    unsigned short* h2    = (unsigned short*)(G + (size_t)41943040);
    float*          fc2p  = (float*)(G + (size_t)50331648);

    // weight prep (fused single launch)
    transpose_all<<<12288, 256, 0, stream>>>(w_qkv, w_proj, w_fc1, w_fc2,
                                             wqkvT, wprojT, wfc1T, wfc2T);

    // h1 = LN(x) fp16 ; qkv16 = fp16(h1 @ w_qkv + b)   (gemm256: 384 blocks)
    ln_kernel<<<4096, 256, 0, stream>>>(x, norm_g, norm_b, h1);
    gemm256<0><<<384, 512, 0, stream>>>(h1, wqkvT, b_qkv, qkv16,
                                        4096, 3072, 1024, 1024, 1024, 3072);

    // compact K (x8-scaled) and V^T
    kv_conv<<<dim3(16, 64), 256, 0, stream>>>(qkv16, K_g, Vt_g);

    // attention -> ctx (fp16), QBLK=64 (1024 blocks = 4/CU)
    attn_kernel<<<dim3(16, 64), 256, 0, stream>>>(qkv16, K_g, Vt_g, ctxb);

    // x1 = x + ctx @ w_proj + b  (2-phase BM=64; x1 lives in d_out)
    gemm_bt<1, 64><<<dim3(8, 64), 256, 0, stream>>>(ctxb, wprojT, b_proj, x, out,
                                                    4096, 1024, 1024, 1024, 1024, 1024);

    // h2 = LN(x1) ; fc1 = gelu(h2 @ w_fc1 + b)   (gemm256: 512 blocks = 2/CU)
    ln_kernel<<<4096, 256, 0, stream>>>(out, norm_g, norm_b, h2);
    gemm256<2><<<512, 512, 0, stream>>>(h2, wfc1T, b_fc1, fc1o,
                                        4096, 4096, 1024, 1024, 1024, 4096);

    // fc2: BM=64 + split-K=2 -> 1024 blocks = 4/CU; then reduce + bias + residual
    gemm_bt<3, 64><<<dim3(8, 64, 2), 256, 0, stream>>>(fc1o, wfc2T, nullptr, nullptr, fc2p,
                                                       4096, 1024, 2048, 4096, 4096, 1024);
    red_kernel<2><<<4096, 256, 0, stream>>>(fc2p, b_fc2, out);
}

// Round 12
// 284.080 us; speedup vs baseline: 1.0739x; 1.0739x over previous
//
#include <hip/hip_runtime.h>
#include <hip/hip_bf16.h>

typedef __attribute__((ext_vector_type(8))) short short8;
typedef __attribute__((ext_vector_type(8))) _Float16 half8;
typedef __attribute__((ext_vector_type(4))) float f32x4;

__device__ __forceinline__ unsigned short f2h(float f) {
    _Float16 h = (_Float16)f;
    return *reinterpret_cast<unsigned short*>(&h);
}
__device__ __forceinline__ float h2f(unsigned short u) {
    _Float16 h = *reinterpret_cast<_Float16*>(&u);
    return (float)h;
}

// async global->LDS, 16B per lane, wave-uniform LDS base + lane*16 dest
__device__ __forceinline__ void gld_lds16(const unsigned short* g, unsigned short* l) {
    __builtin_amdgcn_global_load_lds(
        (const __attribute__((address_space(1))) unsigned int*)g,
        (__attribute__((address_space(3))) unsigned int*)l, 16, 0, 0);
}

// ---------------- fused weight transpose + fp16 convert (one launch) ----------------
__global__ __launch_bounds__(256)
void transpose_all(const float* __restrict__ W0, const float* __restrict__ W1,
                   const float* __restrict__ W2, const float* __restrict__ W3,
                   unsigned short* __restrict__ o0, unsigned short* __restrict__ o1,
                   unsigned short* __restrict__ o2, unsigned short* __restrict__ o3) {
    __shared__ float tile[32][33];
    const int bid = blockIdx.x;
    const float* W; unsigned short* out; int K, N, loc;
    if (bid < 3072)      { W = W0; out = o0; K = 1024; N = 3072; loc = bid; }
    else if (bid < 4096) { W = W1; out = o1; K = 1024; N = 1024; loc = bid - 3072; }
    else if (bid < 8192) { W = W2; out = o2; K = 1024; N = 4096; loc = bid - 4096; }
    else                 { W = W3; out = o3; K = 4096; N = 1024; loc = bid - 8192; }
    const int nx = N >> 5;
    const int n0 = (loc % nx) << 5, k0 = (loc / nx) << 5;
    const int tid = threadIdx.x;
    const int r = tid >> 3, c4 = (tid & 7) << 2;
    float4 v = *reinterpret_cast<const float4*>(W + (size_t)(k0 + r) * N + n0 + c4);
    tile[r][c4 + 0] = v.x; tile[r][c4 + 1] = v.y;
    tile[r][c4 + 2] = v.z; tile[r][c4 + 3] = v.w;
    __syncthreads();
    const int n = n0 + r;
    ushort4 o;
    o.x = f2h(tile[c4 + 0][r]); o.y = f2h(tile[c4 + 1][r]);
    o.z = f2h(tile[c4 + 2][r]); o.w = f2h(tile[c4 + 3][r]);
    *reinterpret_cast<ushort4*>(out + (size_t)n * K + k0 + c4) = o;
}

// ---------------- LayerNorm -> fp16 [row][1024] ----------------
__global__ __launch_bounds__(256)
void ln_kernel(const float* __restrict__ x, const float* __restrict__ gw,
               const float* __restrict__ bw, unsigned short* __restrict__ out) {
    const int row = blockIdx.x, tid = threadIdx.x;
    const float* xr = x + (size_t)row * 1024;
    float4 v = *reinterpret_cast<const float4*>(xr + tid * 4);
    float s = v.x + v.y + v.z + v.w;
    float sq = v.x * v.x + v.y * v.y + v.z * v.z + v.w * v.w;
    #pragma unroll
    for (int off = 1; off < 64; off <<= 1) {
        s  += __shfl_xor(s, off);
        sq += __shfl_xor(sq, off);
    }
    __shared__ float ps[4], pq[4];
    const int wave = tid >> 6;
    if ((tid & 63) == 0) { ps[wave] = s; pq[wave] = sq; }
    __syncthreads();
    s  = ps[0] + ps[1] + ps[2] + ps[3];
    sq = pq[0] + pq[1] + pq[2] + pq[3];
    const float mu = s * (1.0f / 1024.0f);
    const float var = sq * (1.0f / 1024.0f) - mu * mu;
    const float rs = rsqrtf(var + 1e-5f);
    float4 gv = *reinterpret_cast<const float4*>(gw + tid * 4);
    float4 bv = *reinterpret_cast<const float4*>(bw + tid * 4);
    ushort4 o;
    o.x = f2h((v.x - mu) * rs * gv.x + bv.x);
    o.y = f2h((v.y - mu) * rs * gv.y + bv.y);
    o.z = f2h((v.z - mu) * rs * gv.z + bv.z);
    o.w = f2h((v.w - mu) * rs * gv.w + bv.w);
    *reinterpret_cast<ushort4*>(out + (size_t)row * 1024 + tid * 4) = o;
}

// ---------------- mid-tile GEMM: 128x256, BK=32, 8 waves (2Mx4N), 48KB LDS ----------
// 2-phase prefetch (verified gemm_bt structure at bigger shape): stage t+1 before
// compute t, one barrier per K-tile. 48KB LDS -> 3 blocks/CU LDS-limit; fc1 grid 512
// = 2 blocks/CU = 4 waves/SIMD (TLP covers latency, the m97/m114 mechanism).
// Chunk-swizzle (rule 21, same math as gemm_bt): write phys16B = (l&3)^((l>>3)&3),
// read chunk = jq ^ ((fr>>1)&3)  -> 2-way bank conflicts (free).
// EPI 0: fp16 = acc+bias ; EPI 2: fp16 = gelu(acc+bias)
template<int EPI>
__global__ __launch_bounds__(512, 4)
void gemm_mid(const unsigned short* __restrict__ A, const unsigned short* __restrict__ Bt,
              const float* __restrict__ bias, void* Cout,
              int M, int N, int K, int lda, int ldb, int ldc) {
    __shared__ unsigned short As[2][128 * 32];   // 8KB per buf
    __shared__ unsigned short Bs[2][256 * 32];   // 16KB per buf (total 48KB)
    const int tid = threadIdx.x;
    const int wave = tid >> 6, lane = tid & 63;
    // bijective XCD swizzle (gridDim.x % 8 == 0 for our shapes)
    const int nwg = gridDim.x;
    const int swz = (blockIdx.x & 7) * (nwg >> 3) + (blockIdx.x >> 3);
    const int nx = N >> 8;
    const int bm = (swz / nx) << 7, bn = (swz % nx) << 8;
    const int wm = wave >> 2, wn = wave & 3;     // 2 M-waves x 4 N-waves, 64x64 each
    const int fr = lane & 15, g8 = (lane >> 4) << 3, fq = (lane >> 4) << 2;
    const int jq = g8 >> 3;          // logical 16B chunk (0..3)
    const int sx2 = (fr >> 1) & 3;   // read-side XOR

    // staging: A 1 issue/wave (rows wave*16..+15), B 2 issues/wave (rows wave*32..+31).
    // per 1KB issue: lane l -> row base+(l>>2), phys chunk l&3; global source supplies
    // logical chunk (l&3)^((l>>3)&3) (bases are multiples of 16 -> (row>>1)&3=(l>>3)&3).
    const int srow = lane >> 2;
    const int scol = ((lane & 3) ^ ((lane >> 3) & 3)) << 3;
    const unsigned short* gA  = A + (size_t)(bm + wave * 16 + srow) * lda + scol;
    const unsigned short* gB0 = Bt + (size_t)(bn + wave * 32 + srow) * ldb + scol;
    const unsigned short* gB1 = gB0 + (size_t)16 * ldb;
    const int lbA = wave * 512;      // wave-uniform LDS bases (shorts)
    const int lbB = wave * 1024;

    f32x4 acc[4][4];
    #pragma unroll
    for (int m = 0; m < 4; ++m)
        #pragma unroll
        for (int n_ = 0; n_ < 4; ++n_)
            #pragma unroll
            for (int r_ = 0; r_ < 4; ++r_) acc[m][n_][r_] = 0.0f;

    auto stage = [&](int buf, int k0) {
        gld_lds16(gA + k0, &As[buf][lbA]);
        gld_lds16(gB0 + k0, &Bs[buf][lbB]);
        gld_lds16(gB1 + k0, &Bs[buf][lbB + 512]);
    };
    auto compute = [&](int buf) {
        half8 af[4], bfv[4];
        #pragma unroll
        for (int m = 0; m < 4; ++m)
            af[m] = *reinterpret_cast<const half8*>(
                &As[buf][(wm * 64 + m * 16 + fr) * 32 + ((jq ^ sx2) << 3)]);
        #pragma unroll
        for (int n_ = 0; n_ < 4; ++n_)
            bfv[n_] = *reinterpret_cast<const half8*>(
                &Bs[buf][(wn * 64 + n_ * 16 + fr) * 32 + ((jq ^ sx2) << 3)]);
        #pragma unroll
        for (int m = 0; m < 4; ++m)
            #pragma unroll
            for (int n_ = 0; n_ < 4; ++n_)
                acc[m][n_] = __builtin_amdgcn_mfma_f32_16x16x32_f16(af[m], bfv[n_], acc[m][n_], 0, 0, 0);
    };

    const int nt = K >> 5;   // even for all our shapes
    stage(0, 0);
    __syncthreads();
    int k0 = 32;
    for (int t = 0; t < nt - 2; t += 2) {
        stage(1, k0);
        compute(0);
        __syncthreads();
        stage(0, k0 + 32);
        compute(1);
        __syncthreads();
        k0 += 64;
    }
    stage(1, k0);
    compute(0);
    __syncthreads();
    compute(1);

    unsigned short* o16 = reinterpret_cast<unsigned short*>(Cout);
    #pragma unroll
    for (int n_ = 0; n_ < 4; ++n_) {
        const int col = bn + wn * 64 + n_ * 16 + fr;
        const float bc = bias[col];
        #pragma unroll
        for (int m = 0; m < 4; ++m) {
            #pragma unroll
            for (int r_ = 0; r_ < 4; ++r_) {
                const int row = bm + wm * 64 + m * 16 + fq + r_;
                const size_t idx = (size_t)row * ldc + col;
                float v = acc[m][n_][r_] + bc;
                if (EPI == 0) {
                    o16[idx] = f2h(v);
                } else {
                    float ge = 0.5f * v * (1.0f + erff(v * 0.70710678118654752f));
                    o16[idx] = f2h(ge);
                }
            }
        }
    }
}

// ---------------- 2-phase GEMM (skinny shapes), BK=32 chunk-swizzle -----------------
// EPI 1: f32 = acc+bias+resid ; EPI 4: fp16 partial (split-K over blockIdx.z)
template<int EPI, int BM>
__global__ __launch_bounds__(256)
void gemm_bt(const unsigned short* __restrict__ A, const unsigned short* __restrict__ Bt,
             const float* __restrict__ bias, const float* resid,
             void* Cout, int M, int N, int K, int lda, int ldb, int ldc) {
    constexpr int MF = BM / 32;
    __shared__ unsigned short As[2][BM * 32];
    __shared__ unsigned short Bs[2][128 * 32];
    const int tid = threadIdx.x;
    const int wave = tid >> 6, lane = tid & 63;
    const int bm = blockIdx.y * BM, bn = blockIdx.x << 7;
    const int wr = (wave >> 1) * (BM / 2), wc = (wave & 1) << 6;
    const int fr = lane & 15, g8 = (lane >> 4) << 3, fq = (lane >> 4) << 2;
    const int jq = g8 >> 3, sx2 = (fr >> 1) & 3;
    const size_t koff = (EPI >= 3) ? (size_t)blockIdx.z * K : 0;

    const int srowA = (BM == 128) ? ((wave << 5) + (lane >> 2)) : ((wave << 4) + (lane >> 2));
    const int srowB = (wave << 5) + (lane >> 2);
    const int scol = (((lane & 3) ^ ((lane >> 3) & 3))) << 3;
    const unsigned short* gA0 = A + (size_t)(bm + srowA) * lda + scol + koff;
    const unsigned short* gA1 = gA0 + (size_t)16 * lda;      // BM==128 only
    const unsigned short* gB0 = Bt + (size_t)(bn + srowB) * ldb + scol + koff;
    const unsigned short* gB1 = gB0 + (size_t)16 * ldb;

    f32x4 acc[MF][4];
    #pragma unroll
    for (int m = 0; m < MF; ++m)
        #pragma unroll
        for (int n = 0; n < 4; ++n)
            #pragma unroll
            for (int r = 0; r < 4; ++r) acc[m][n][r] = 0.0f;

    auto stage = [&](int buf, int k0) {
        unsigned short* lA = &As[buf][(BM == 128) ? (wave << 10) : (wave << 9)];
        unsigned short* lB = &Bs[buf][wave << 10];
        gld_lds16(gA0 + k0, lA);
        if constexpr (BM == 128) gld_lds16(gA1 + k0, lA + 512);
        gld_lds16(gB0 + k0, lB);
        gld_lds16(gB1 + k0, lB + 512);
    };
    auto compute = [&](int buf) {
        half8 af[MF], bfv[4];
        #pragma unroll
        for (int m = 0; m < MF; ++m)
            af[m] = *reinterpret_cast<const half8*>(
                &As[buf][(wr + m * 16 + fr) * 32 + ((jq ^ sx2) << 3)]);
        #pragma unroll
        for (int n = 0; n < 4; ++n)
            bfv[n] = *reinterpret_cast<const half8*>(
                &Bs[buf][(wc + n * 16 + fr) * 32 + ((jq ^ sx2) << 3)]);
        #pragma unroll
        for (int m = 0; m < MF; ++m)
            #pragma unroll
            for (int n = 0; n < 4; ++n)
                acc[m][n] = __builtin_amdgcn_mfma_f32_16x16x32_f16(af[m], bfv[n], acc[m][n], 0, 0, 0);
    };

    const int nt = K >> 5;
    stage(0, 0);
    __syncthreads();
    int k0 = 32;
    for (int t = 0; t < nt - 2; t += 2) {
        stage(1, k0);
        compute(0);
        __syncthreads();
        stage(0, k0 + 32);
        compute(1);
        __syncthreads();
        k0 += 64;
    }
    stage(1, k0);
    compute(0);
    __syncthreads();
    compute(1);

    if (EPI == 4) {
        unsigned short* P = reinterpret_cast<unsigned short*>(Cout) +
                            (size_t)blockIdx.z * (size_t)M * ldc;
        #pragma unroll
        for (int n = 0; n < 4; ++n) {
            const int col = bn + wc + n * 16 + fr;
            #pragma unroll
            for (int m = 0; m < MF; ++m)
                #pragma unroll
                for (int r = 0; r < 4; ++r) {
                    const int row = bm + wr + m * 16 + fq + r;
                    P[(size_t)row * ldc + col] = f2h(acc[m][n][r]);
                }
        }
        return;
    }

    #pragma unroll
    for (int n = 0; n < 4; ++n) {
        const int col = bn + wc + n * 16 + fr;
        const float bc = bias[col];
        #pragma unroll
        for (int m = 0; m < MF; ++m) {
            #pragma unroll
            for (int r = 0; r < 4; ++r) {
                const int row = bm + wr + m * 16 + fq + r;
                const size_t idx = (size_t)row * ldc + col;
                float v = acc[m][n][r] + bc;
                reinterpret_cast<float*>(Cout)[idx] = v + resid[idx];   // EPI 1
            }
        }
    }
}

// ---------------- split-K reduce (fp16 partials): out = out + bias + sum_z p[z] -----
template<int Z>
__global__ __launch_bounds__(256)
void red_h(const unsigned short* __restrict__ p, const float* __restrict__ bias,
           float* out) {
    const size_t MN = (size_t)4096 * 1024;
    const size_t i = ((size_t)blockIdx.x * 256 + threadIdx.x) * 4;
    float4 r  = *reinterpret_cast<const float4*>(out + i);
    float4 bb = *reinterpret_cast<const float4*>(bias + (i & 1023));
    float o0 = r.x + bb.x, o1 = r.y + bb.y, o2 = r.z + bb.z, o3 = r.w + bb.w;
    #pragma unroll
    for (int z = 0; z < Z; ++z) {
        ushort4 a = *reinterpret_cast<const ushort4*>(p + (size_t)z * MN + i);
        o0 += h2f(a.x); o1 += h2f(a.y); o2 += h2f(a.z); o3 += h2f(a.w);
    }
    float4 o; o.x = o0; o.y = o1; o.z = o2; o.w = o3;
    *reinterpret_cast<float4*>(out + i) = o;
}

// ---------------- K/V compaction ----------------
__global__ __launch_bounds__(256)
void kv_conv(const unsigned short* __restrict__ qkv16, unsigned short* __restrict__ K_g,
             unsigned short* __restrict__ Vt_g) {
    __shared__ unsigned short VtT[64][72];
    const int kc = blockIdx.x;
    const int bh = blockIdx.y;
    const int b = bh >> 4, h = bh & 15;
    const int tid = threadIdx.x;
    const int key = tid >> 2, c16 = (tid & 3) << 4;
    const unsigned short* kp = qkv16 + ((size_t)(b * 1024 + kc * 64 + key)) * 3072 + 1024 + h * 64 + c16;
    alignas(16) unsigned short kbuf[16];
    #pragma unroll
    for (int j = 0; j < 16; j += 8) {
        short8 k8 = *reinterpret_cast<const short8*>(kp + j);
        short8 v8 = *reinterpret_cast<const short8*>(kp + 1024 + j);
        #pragma unroll
        for (int c = 0; c < 8; ++c) {
            kbuf[j + c] = f2h(8.0f * h2f((unsigned short)k8[c]));
            VtT[c16 + j + c][key] = (unsigned short)v8[c];
        }
    }
    const size_t kb = ((size_t)bh * 1024 + kc * 64 + key) * 64 + c16;
    *reinterpret_cast<short8*>(K_g + kb)     = *reinterpret_cast<short8*>(&kbuf[0]);
    *reinterpret_cast<short8*>(K_g + kb + 8) = *reinterpret_cast<short8*>(&kbuf[8]);
    __syncthreads();
    const int d = tid >> 2;
    const size_t vb = ((size_t)bh * 64 + d) * 1024 + (size_t)kc * 64 + c16;
    *reinterpret_cast<short8*>(Vt_g + vb)     = *reinterpret_cast<const short8*>(&VtT[d][c16]);
    *reinterpret_cast<short8*>(Vt_g + vb + 8) = *reinterpret_cast<const short8*>(&VtT[d][c16 + 8]);
}

// ---------------- Flash attention (fp16, QBLK=64, T14 register prefetch) ----------------
__global__ __launch_bounds__(256)
void attn_kernel(const unsigned short* __restrict__ qkv16,
                 const unsigned short* __restrict__ K_g,
                 const unsigned short* __restrict__ Vt_g,
                 unsigned short* __restrict__ ctx) {
    __shared__ unsigned short Kh[64][72];
    __shared__ unsigned short Vt[64][72];
    __shared__ unsigned short Plds[4][16][72];
    const int qt = blockIdx.x;
    const int bh = blockIdx.y;
    const int b = bh >> 4, h = bh & 15;
    const int tid = threadIdx.x;
    const int wave = tid >> 6, lane = tid & 63;
    const int fr = lane & 15, g8 = (lane >> 4) << 3, fq = (lane >> 4) << 2;

    const int qrow = qt * 64 + wave * 16 + fr;
    const unsigned short* qp = qkv16 + ((size_t)(b * 1024 + qrow)) * 3072 + h * 64;
    half8 qf[2];
    qf[0] = *reinterpret_cast<const half8*>(qp + g8);
    qf[1] = *reinterpret_cast<const half8*>(qp + 32 + g8);

    float mrun[4], lrun[4];
    f32x4 cacc[4];
    #pragma unroll
    for (int r = 0; r < 4; ++r) { mrun[r] = -3.0e38f; lrun[r] = 0.0f; }
    #pragma unroll
    for (int nd = 0; nd < 4; ++nd)
        #pragma unroll
        for (int r = 0; r < 4; ++r) cacc[nd][r] = 0.0f;

    const int skey = tid >> 2, sc16 = (tid & 3) << 4;
    const unsigned short* kgp = K_g + ((size_t)bh * 1024 + skey) * 64 + sc16;
    const unsigned short* vgp = Vt_g + ((size_t)bh * 64 + skey) * 1024 + sc16;

    short8 ka = *reinterpret_cast<const short8*>(kgp);
    short8 kb = *reinterpret_cast<const short8*>(kgp + 8);
    short8 va = *reinterpret_cast<const short8*>(vgp);
    short8 vb = *reinterpret_cast<const short8*>(vgp + 8);

    for (int kt = 0; kt < 16; ++kt) {
        __syncthreads();
        *reinterpret_cast<short8*>(&Kh[skey][sc16])     = ka;
        *reinterpret_cast<short8*>(&Kh[skey][sc16 + 8]) = kb;
        *reinterpret_cast<short8*>(&Vt[skey][sc16])     = va;
        *reinterpret_cast<short8*>(&Vt[skey][sc16 + 8]) = vb;
        __syncthreads();
        const int ktn = (kt < 15) ? kt + 1 : 15;
        ka = *reinterpret_cast<const short8*>(kgp + (size_t)ktn * 4096);
        kb = *reinterpret_cast<const short8*>(kgp + (size_t)ktn * 4096 + 8);
        va = *reinterpret_cast<const short8*>(vgp + ktn * 64);
        vb = *reinterpret_cast<const short8*>(vgp + ktn * 64 + 8);

        f32x4 S[4];
        #pragma unroll
        for (int n = 0; n < 4; ++n)
            #pragma unroll
            for (int r = 0; r < 4; ++r) S[n][r] = 0.0f;
        #pragma unroll
        for (int s_ = 0; s_ < 2; ++s_)
            #pragma unroll
            for (int n = 0; n < 4; ++n) {
                half8 kh = *reinterpret_cast<const half8*>(&Kh[n * 16 + fr][s_ * 32 + g8]);
                S[n] = __builtin_amdgcn_mfma_f32_16x16x32_f16(qf[s_], kh, S[n], 0, 0, 0);
            }

        float mt[4];
        #pragma unroll
        for (int r = 0; r < 4; ++r)
            mt[r] = fmaxf(fmaxf(S[0][r], S[1][r]), fmaxf(S[2][r], S[3][r]));
        #pragma unroll
        for (int r = 0; r < 4; ++r) {
            mt[r] = fmaxf(mt[r], __shfl_xor(mt[r], 1));
            mt[r] = fmaxf(mt[r], __shfl_xor(mt[r], 2));
            mt[r] = fmaxf(mt[r], __shfl_xor(mt[r], 4));
            mt[r] = fmaxf(mt[r], __shfl_xor(mt[r], 8));
        }
        float P[4][4], rsum[4];
        #pragma unroll
        for (int r = 0; r < 4; ++r) {
            float mnew = fmaxf(mrun[r], mt[r]);
            float sf = __expf(mrun[r] - mnew);
            mrun[r] = mnew;
            rsum[r] = 0.0f;
            #pragma unroll
            for (int n = 0; n < 4; ++n) {
                float p = __expf(S[n][r] - mnew);
                P[n][r] = p;
                rsum[r] += p;
            }
            lrun[r] *= sf;
            #pragma unroll
            for (int nd = 0; nd < 4; ++nd) cacc[nd][r] *= sf;
        }
        #pragma unroll
        for (int r = 0; r < 4; ++r) {
            rsum[r] += __shfl_xor(rsum[r], 1);
            rsum[r] += __shfl_xor(rsum[r], 2);
            rsum[r] += __shfl_xor(rsum[r], 4);
            rsum[r] += __shfl_xor(rsum[r], 8);
            lrun[r] += rsum[r];
        }
        #pragma unroll
        for (int n = 0; n < 4; ++n)
            #pragma unroll
            for (int r = 0; r < 4; ++r)
                Plds[wave][fq + r][n * 16 + fr] = f2h(P[n][r]);
        #pragma unroll
        for (int s_ = 0; s_ < 2; ++s_) {
            half8 pa = *reinterpret_cast<const half8*>(&Plds[wave][fr][s_ * 32 + g8]);
            #pragma unroll
            for (int nd = 0; nd < 4; ++nd) {
                half8 vb8 = *reinterpret_cast<const half8*>(&Vt[nd * 16 + fr][s_ * 32 + g8]);
                cacc[nd] = __builtin_amdgcn_mfma_f32_16x16x32_f16(pa, vb8, cacc[nd], 0, 0, 0);
            }
        }
    }
    #pragma unroll
    for (int r = 0; r < 4; ++r) {
        const float inv = 1.0f / lrun[r];
        const int row = qt * 64 + wave * 16 + fq + r;
        unsigned short* cp = ctx + ((size_t)(b * 1024 + row)) * 1024 + h * 64;
        #pragma unroll
        for (int nd = 0; nd < 4; ++nd)
            cp[nd * 16 + fr] = f2h(cacc[nd][r] * inv);
    }
}

// ---------------- launch ----------------
extern "C" void kernel_launch(void* const* d_in, const int* in_sizes, int n_in,
                              void* d_out, int out_size, void* d_ws, size_t ws_size,
                              hipStream_t stream) {
    const float* x      = (const float*)d_in[0];
    const float* norm_g = (const float*)d_in[1];
    const float* norm_b = (const float*)d_in[2];
    const float* w_qkv  = (const float*)d_in[3];
    const float* b_qkv  = (const float*)d_in[4];
    const float* w_proj = (const float*)d_in[5];
    const float* b_proj = (const float*)d_in[6];
    const float* w_fc1  = (const float*)d_in[7];
    const float* b_fc1  = (const float*)d_in[8];
    const float* w_fc2  = (const float*)d_in[9];
    const float* b_fc2  = (const float*)d_in[10];
    float* out = (float*)d_out;
    char* ws = (char*)d_ws;

    size_t off = 0;
    unsigned short* wqkvT  = (unsigned short*)(ws + off); off += (size_t)3072 * 1024 * 2;
    unsigned short* wprojT = (unsigned short*)(ws + off); off += (size_t)1024 * 1024 * 2;
    unsigned short* wfc1T  = (unsigned short*)(ws + off); off += (size_t)4096 * 1024 * 2;
    unsigned short* wfc2T  = (unsigned short*)(ws + off); off += (size_t)1024 * 4096 * 2;
    unsigned short* ctxb   = (unsigned short*)(ws + off); off += (size_t)4096 * 1024 * 2;
    char* G = ws + off;
    // G region timeline (byte offsets; total usage <= 117.4MB as in all passing rounds):
    //   h1     ( 8.4 MB) at G+0         : ln -> qkv GEMM
    //   qkv16  (25.2 MB) at G+8388608   : qkv GEMM -> attn / kv_conv
    //   K_g    ( 8.4 MB) at G+0         : kv_conv -> attn (overlaps dead h1)
    //   Vt_g   ( 8.4 MB) at G+33554432  : kv_conv -> attn
    //   fc1o   (33.5 MB) at G+0         : fc1 -> fc2
    //   h2     ( 8.4 MB) at G+41943040  : ln2 -> fc1 (dead before fc2)
    //   fc2ph  [4][4096][1024] fp16 (33.5 MB) at G+33554432 : fc2 partials -> red
    //          (overlaps dead Vt_g/h2; ends at G+67.1MB < prior 83.9MB watermark)
    unsigned short* h1    = (unsigned short*)G;
    unsigned short* qkv16 = (unsigned short*)(G + (size_t)8388608);
    unsigned short* K_g   = (unsigned short*)G;
    unsigned short* Vt_g  = (unsigned short*)(G + (size_t)33554432);
    unsigned short* fc1o  = (unsigned short*)G;
    unsigned short* h2    = (unsigned short*)(G + (size_t)41943040);
    unsigned short* fc2ph = (unsigned short*)(G + (size_t)33554432);

    // weight prep (fused single launch)
    transpose_all<<<12288, 256, 0, stream>>>(w_qkv, w_proj, w_fc1, w_fc2,
                                             wqkvT, wprojT, wfc1T, wfc2T);

    // h1 = LN(x) fp16 ; qkv16 = fp16(h1 @ w_qkv + b)   (gemm_mid: 384 blocks = 1.5/CU)
    ln_kernel<<<4096, 256, 0, stream>>>(x, norm_g, norm_b, h1);
    gemm_mid<0><<<384, 512, 0, stream>>>(h1, wqkvT, b_qkv, qkv16,
                                         4096, 3072, 1024, 1024, 1024, 3072);

    // compact K (x8-scaled) and V^T
    kv_conv<<<dim3(16, 64), 256, 0, stream>>>(qkv16, K_g, Vt_g);

    // attention -> ctx (fp16), QBLK=64 (1024 blocks = 4/CU)
    attn_kernel<<<dim3(16, 64), 256, 0, stream>>>(qkv16, K_g, Vt_g, ctxb);

    // x1 = x + ctx @ w_proj + b  (2-phase BM=64; x1 lives in d_out)
    gemm_bt<1, 64><<<dim3(8, 64), 256, 0, stream>>>(ctxb, wprojT, b_proj, x, out,
                                                    4096, 1024, 1024, 1024, 1024, 1024);

    // h2 = LN(x1) ; fc1 = gelu(h2 @ w_fc1 + b)   (gemm_mid: 512 blocks = 2/CU)
    ln_kernel<<<4096, 256, 0, stream>>>(out, norm_g, norm_b, h2);
    gemm_mid<2><<<512, 512, 0, stream>>>(h2, wfc1T, b_fc1, fc1o,
                                         4096, 4096, 1024, 1024, 1024, 4096);

    // fc2: BM=64, split-K=4 (2048 blocks = 8/CU), fp16 partials; then reduce
    gemm_bt<4, 64><<<dim3(8, 64, 4), 256, 0, stream>>>(fc1o, wfc2T, nullptr, nullptr, fc2ph,
                                                       4096, 1024, 1024, 4096, 4096, 1024);
    red_h<4><<<4096, 256, 0, stream>>>(fc2ph, b_fc2, out);
}

// Round 13
// 262.281 us; speedup vs baseline: 1.1631x; 1.0831x over previous
//
#include <hip/hip_runtime.h>
#include <hip/hip_bf16.h>

typedef __attribute__((ext_vector_type(8))) short short8;
typedef __attribute__((ext_vector_type(8))) _Float16 half8;
typedef __attribute__((ext_vector_type(4))) float f32x4;

__device__ __forceinline__ unsigned short f2h(float f) {
    _Float16 h = (_Float16)f;
    return *reinterpret_cast<unsigned short*>(&h);
}
__device__ __forceinline__ float h2f(unsigned short u) {
    _Float16 h = *reinterpret_cast<_Float16*>(&u);
    return (float)h;
}

// async global->LDS, 16B per lane, wave-uniform LDS base + lane*16 dest
__device__ __forceinline__ void gld_lds16(const unsigned short* g, unsigned short* l) {
    __builtin_amdgcn_global_load_lds(
        (const __attribute__((address_space(1))) unsigned int*)g,
        (__attribute__((address_space(3))) unsigned int*)l, 16, 0, 0);
}

// ---------------- fused weight transpose + fp16 convert (one launch) ----------------
__global__ __launch_bounds__(256)
void transpose_all(const float* __restrict__ W0, const float* __restrict__ W1,
                   const float* __restrict__ W2, const float* __restrict__ W3,
                   unsigned short* __restrict__ o0, unsigned short* __restrict__ o1,
                   unsigned short* __restrict__ o2, unsigned short* __restrict__ o3) {
    __shared__ float tile[32][33];
    const int bid = blockIdx.x;
    const float* W; unsigned short* out; int K, N, loc;
    if (bid < 3072)      { W = W0; out = o0; K = 1024; N = 3072; loc = bid; }
    else if (bid < 4096) { W = W1; out = o1; K = 1024; N = 1024; loc = bid - 3072; }
    else if (bid < 8192) { W = W2; out = o2; K = 1024; N = 4096; loc = bid - 4096; }
    else                 { W = W3; out = o3; K = 4096; N = 1024; loc = bid - 8192; }
    const int nx = N >> 5;
    const int n0 = (loc % nx) << 5, k0 = (loc / nx) << 5;
    const int tid = threadIdx.x;
    const int r = tid >> 3, c4 = (tid & 7) << 2;
    float4 v = *reinterpret_cast<const float4*>(W + (size_t)(k0 + r) * N + n0 + c4);
    tile[r][c4 + 0] = v.x; tile[r][c4 + 1] = v.y;
    tile[r][c4 + 2] = v.z; tile[r][c4 + 3] = v.w;
    __syncthreads();
    const int n = n0 + r;
    ushort4 o;
    o.x = f2h(tile[c4 + 0][r]); o.y = f2h(tile[c4 + 1][r]);
    o.z = f2h(tile[c4 + 2][r]); o.w = f2h(tile[c4 + 3][r]);
    *reinterpret_cast<ushort4*>(out + (size_t)n * K + k0 + c4) = o;
}

// ---------------- LayerNorm -> fp16 [row][1024] ----------------
__global__ __launch_bounds__(256)
void ln_kernel(const float* __restrict__ x, const float* __restrict__ gw,
               const float* __restrict__ bw, unsigned short* __restrict__ out) {
    const int row = blockIdx.x, tid = threadIdx.x;
    const float* xr = x + (size_t)row * 1024;
    float4 v = *reinterpret_cast<const float4*>(xr + tid * 4);
    float s = v.x + v.y + v.z + v.w;
    float sq = v.x * v.x + v.y * v.y + v.z * v.z + v.w * v.w;
    #pragma unroll
    for (int off = 1; off < 64; off <<= 1) {
        s  += __shfl_xor(s, off);
        sq += __shfl_xor(sq, off);
    }
    __shared__ float ps[4], pq[4];
    const int wave = tid >> 6;
    if ((tid & 63) == 0) { ps[wave] = s; pq[wave] = sq; }
    __syncthreads();
    s  = ps[0] + ps[1] + ps[2] + ps[3];
    sq = pq[0] + pq[1] + pq[2] + pq[3];
    const float mu = s * (1.0f / 1024.0f);
    const float var = sq * (1.0f / 1024.0f) - mu * mu;
    const float rs = rsqrtf(var + 1e-5f);
    float4 gv = *reinterpret_cast<const float4*>(gw + tid * 4);
    float4 bv = *reinterpret_cast<const float4*>(bw + tid * 4);
    ushort4 o;
    o.x = f2h((v.x - mu) * rs * gv.x + bv.x);
    o.y = f2h((v.y - mu) * rs * gv.y + bv.y);
    o.z = f2h((v.z - mu) * rs * gv.z + bv.z);
    o.w = f2h((v.w - mu) * rs * gv.w + bv.w);
    *reinterpret_cast<ushort4*>(out + (size_t)row * 1024 + tid * 4) = o;
}

// ---------------- mid-tile GEMM: 128x256, BK=32, 8 waves (2Mx4N), 48KB LDS ----------
// 2-phase prefetch; one barrier per K-tile; chunk-swizzled LDS (2-way conflicts, free).
// NZ==1: XCD swizzle = per-XCD contiguous bm stripes (A-tile sharers co-XCD).
// NZ>1 (split-K): remap so xcd = bm%8, bn fastest -> all bn-sharers of an A-tile
//   are co-resident on one XCD (fixes fc2's 136MB FETCH from cross-XCD A re-reads).
// EPI 0: fp16 = acc+bias ; EPI 2: fp16 = gelu(acc+bias) ; EPI 4: fp16 raw partial
template<int EPI, int NZ>
__global__ __launch_bounds__(512, 4)
void gemm_mid(const unsigned short* __restrict__ A, const unsigned short* __restrict__ Bt,
              const float* __restrict__ bias, void* Cout,
              int M, int N, int K, int lda, int ldb, int ldc) {
    __shared__ unsigned short As[2][128 * 32];   // 8KB per buf
    __shared__ unsigned short Bs[2][256 * 32];   // 16KB per buf (total 48KB)
    const int tid = threadIdx.x;
    const int wave = tid >> 6, lane = tid & 63;
    const int nx = N >> 8;
    int bm, bn, z;
    if (NZ == 1) {
        const int nwg = gridDim.x;
        const int swz = (blockIdx.x & 7) * (nwg >> 3) + (blockIdx.x >> 3);
        bm = (swz / nx) << 7; bn = (swz % nx) << 8; z = 0;
    } else {
        // xcd = bid&7 == bm low bits; within XCD: bn fastest, then z, then bm_high
        int bid = blockIdx.x;
        const int xcd = bid & 7; int rest = bid >> 3;
        bn = (rest % nx) << 8; rest /= nx;
        z = rest % NZ; rest /= NZ;
        bm = (rest * 8 + xcd) << 7;              // requires (M/128) % 8 == 0
    }
    const size_t koff = (size_t)z * K;
    const int wm = wave >> 2, wn = wave & 3;     // 2 M-waves x 4 N-waves, 64x64 each
    const int fr = lane & 15, g8 = (lane >> 4) << 3, fq = (lane >> 4) << 2;
    const int jq = g8 >> 3;          // logical 16B chunk (0..3)
    const int sx2 = (fr >> 1) & 3;   // read-side XOR

    const int srow = lane >> 2;
    const int scol = ((lane & 3) ^ ((lane >> 3) & 3)) << 3;
    const unsigned short* gA  = A + (size_t)(bm + wave * 16 + srow) * lda + scol + koff;
    const unsigned short* gB0 = Bt + (size_t)(bn + wave * 32 + srow) * ldb + scol + koff;
    const unsigned short* gB1 = gB0 + (size_t)16 * ldb;
    const int lbA = wave * 512;      // wave-uniform LDS bases (shorts)
    const int lbB = wave * 1024;

    f32x4 acc[4][4];
    #pragma unroll
    for (int m = 0; m < 4; ++m)
        #pragma unroll
        for (int n_ = 0; n_ < 4; ++n_)
            #pragma unroll
            for (int r_ = 0; r_ < 4; ++r_) acc[m][n_][r_] = 0.0f;

    auto stage = [&](int buf, int k0) {
        gld_lds16(gA + k0, &As[buf][lbA]);
        gld_lds16(gB0 + k0, &Bs[buf][lbB]);
        gld_lds16(gB1 + k0, &Bs[buf][lbB + 512]);
    };
    auto compute = [&](int buf) {
        half8 af[4], bfv[4];
        #pragma unroll
        for (int m = 0; m < 4; ++m)
            af[m] = *reinterpret_cast<const half8*>(
                &As[buf][(wm * 64 + m * 16 + fr) * 32 + ((jq ^ sx2) << 3)]);
        #pragma unroll
        for (int n_ = 0; n_ < 4; ++n_)
            bfv[n_] = *reinterpret_cast<const half8*>(
                &Bs[buf][(wn * 64 + n_ * 16 + fr) * 32 + ((jq ^ sx2) << 3)]);
        #pragma unroll
        for (int m = 0; m < 4; ++m)
            #pragma unroll
            for (int n_ = 0; n_ < 4; ++n_)
                acc[m][n_] = __builtin_amdgcn_mfma_f32_16x16x32_f16(af[m], bfv[n_], acc[m][n_], 0, 0, 0);
    };

    const int nt = K >> 5;   // even for all our shapes
    stage(0, 0);
    __syncthreads();
    int k0 = 32;
    for (int t = 0; t < nt - 2; t += 2) {
        stage(1, k0);
        compute(0);
        __syncthreads();
        stage(0, k0 + 32);
        compute(1);
        __syncthreads();
        k0 += 64;
    }
    stage(1, k0);
    compute(0);
    __syncthreads();
    compute(1);

    if (EPI == 4) {
        unsigned short* P = reinterpret_cast<unsigned short*>(Cout) +
                            (size_t)z * (size_t)M * ldc;
        #pragma unroll
        for (int n_ = 0; n_ < 4; ++n_) {
            const int col = bn + wn * 64 + n_ * 16 + fr;
            #pragma unroll
            for (int m = 0; m < 4; ++m)
                #pragma unroll
                for (int r_ = 0; r_ < 4; ++r_) {
                    const int row = bm + wm * 64 + m * 16 + fq + r_;
                    P[(size_t)row * ldc + col] = f2h(acc[m][n_][r_]);
                }
        }
        return;
    }

    unsigned short* o16 = reinterpret_cast<unsigned short*>(Cout);
    #pragma unroll
    for (int n_ = 0; n_ < 4; ++n_) {
        const int col = bn + wn * 64 + n_ * 16 + fr;
        const float bc = bias[col];
        #pragma unroll
        for (int m = 0; m < 4; ++m) {
            #pragma unroll
            for (int r_ = 0; r_ < 4; ++r_) {
                const int row = bm + wm * 64 + m * 16 + fq + r_;
                const size_t idx = (size_t)row * ldc + col;
                float v = acc[m][n_][r_] + bc;
                if (EPI == 0) {
                    o16[idx] = f2h(v);
                } else {
                    float ge = 0.5f * v * (1.0f + erff(v * 0.70710678118654752f));
                    o16[idx] = f2h(ge);
                }
            }
        }
    }
}

// ---------------- 2-phase GEMM (skinny shapes), BK=32 chunk-swizzle -----------------
// REMAP=1: 1-D grid, xcd = bid&7 == bm%8, bn fastest within XCD (A-tile sharers
// co-resident on one XCD). EPI 1: f32 = acc+bias+resid.
template<int EPI, int BM, int REMAP>
__global__ __launch_bounds__(256)
void gemm_bt(const unsigned short* __restrict__ A, const unsigned short* __restrict__ Bt,
             const float* __restrict__ bias, const float* resid,
             void* Cout, int M, int N, int K, int lda, int ldb, int ldc) {
    constexpr int MF = BM / 32;
    __shared__ unsigned short As[2][BM * 32];
    __shared__ unsigned short Bs[2][128 * 32];
    const int tid = threadIdx.x;
    const int wave = tid >> 6, lane = tid & 63;
    int bm, bn;
    if (REMAP) {
        const int nxr = N >> 7;
        int bid = blockIdx.x;
        const int xcd = bid & 7; int rest = bid >> 3;
        bn = (rest % nxr) << 7; rest /= nxr;
        bm = (rest * 8 + xcd) * BM;              // requires (M/BM) % 8 == 0
    } else {
        bm = blockIdx.y * BM; bn = blockIdx.x << 7;
    }
    const int wr = (wave >> 1) * (BM / 2), wc = (wave & 1) << 6;
    const int fr = lane & 15, g8 = (lane >> 4) << 3, fq = (lane >> 4) << 2;
    const int jq = g8 >> 3, sx2 = (fr >> 1) & 3;

    const int srowA = (BM == 128) ? ((wave << 5) + (lane >> 2)) : ((wave << 4) + (lane >> 2));
    const int srowB = (wave << 5) + (lane >> 2);
    const int scol = (((lane & 3) ^ ((lane >> 3) & 3))) << 3;
    const unsigned short* gA0 = A + (size_t)(bm + srowA) * lda + scol;
    const unsigned short* gA1 = gA0 + (size_t)16 * lda;      // BM==128 only
    const unsigned short* gB0 = Bt + (size_t)(bn + srowB) * ldb + scol;
    const unsigned short* gB1 = gB0 + (size_t)16 * ldb;

    f32x4 acc[MF][4];
    #pragma unroll
    for (int m = 0; m < MF; ++m)
        #pragma unroll
        for (int n = 0; n < 4; ++n)
            #pragma unroll
            for (int r = 0; r < 4; ++r) acc[m][n][r] = 0.0f;

    auto stage = [&](int buf, int k0) {
        unsigned short* lA = &As[buf][(BM == 128) ? (wave << 10) : (wave << 9)];
        unsigned short* lB = &Bs[buf][wave << 10];
        gld_lds16(gA0 + k0, lA);
        if constexpr (BM == 128) gld_lds16(gA1 + k0, lA + 512);
        gld_lds16(gB0 + k0, lB);
        gld_lds16(gB1 + k0, lB + 512);
    };
    auto compute = [&](int buf) {
        half8 af[MF], bfv[4];
        #pragma unroll
        for (int m = 0; m < MF; ++m)
            af[m] = *reinterpret_cast<const half8*>(
                &As[buf][(wr + m * 16 + fr) * 32 + ((jq ^ sx2) << 3)]);
        #pragma unroll
        for (int n = 0; n < 4; ++n)
            bfv[n] = *reinterpret_cast<const half8*>(
                &Bs[buf][(wc + n * 16 + fr) * 32 + ((jq ^ sx2) << 3)]);
        #pragma unroll
        for (int m = 0; m < MF; ++m)
            #pragma unroll
            for (int n = 0; n < 4; ++n)
                acc[m][n] = __builtin_amdgcn_mfma_f32_16x16x32_f16(af[m], bfv[n], acc[m][n], 0, 0, 0);
    };

    const int nt = K >> 5;
    stage(0, 0);
    __syncthreads();
    int k0 = 32;
    for (int t = 0; t < nt - 2; t += 2) {
        stage(1, k0);
        compute(0);
        __syncthreads();
        stage(0, k0 + 32);
        compute(1);
        __syncthreads();
        k0 += 64;
    }
    stage(1, k0);
    compute(0);
    __syncthreads();
    compute(1);

    #pragma unroll
    for (int n = 0; n < 4; ++n) {
        const int col = bn + wc + n * 16 + fr;
        const float bc = bias[col];
        #pragma unroll
        for (int m = 0; m < MF; ++m) {
            #pragma unroll
            for (int r = 0; r < 4; ++r) {
                const int row = bm + wr + m * 16 + fq + r;
                const size_t idx = (size_t)row * ldc + col;
                float v = acc[m][n][r] + bc;
                reinterpret_cast<float*>(Cout)[idx] = v + resid[idx];   // EPI 1
            }
        }
    }
}

// ---------------- split-K reduce (fp16 partials): out = out + bias + sum_z p[z] -----
template<int Z>
__global__ __launch_bounds__(256)
void red_h(const unsigned short* __restrict__ p, const float* __restrict__ bias,
           float* out) {
    const size_t MN = (size_t)4096 * 1024;
    const size_t i = ((size_t)blockIdx.x * 256 + threadIdx.x) * 4;
    float4 r  = *reinterpret_cast<const float4*>(out + i);
    float4 bb = *reinterpret_cast<const float4*>(bias + (i & 1023));
    float o0 = r.x + bb.x, o1 = r.y + bb.y, o2 = r.z + bb.z, o3 = r.w + bb.w;
    #pragma unroll
    for (int z = 0; z < Z; ++z) {
        ushort4 a = *reinterpret_cast<const ushort4*>(p + (size_t)z * MN + i);
        o0 += h2f(a.x); o1 += h2f(a.y); o2 += h2f(a.z); o3 += h2f(a.w);
    }
    float4 o; o.x = o0; o.y = o1; o.z = o2; o.w = o3;
    *reinterpret_cast<float4*>(out + i) = o;
}

// ---------------- K/V compaction ----------------
__global__ __launch_bounds__(256)
void kv_conv(const unsigned short* __restrict__ qkv16, unsigned short* __restrict__ K_g,
             unsigned short* __restrict__ Vt_g) {
    __shared__ unsigned short VtT[64][72];
    const int kc = blockIdx.x;
    const int bh = blockIdx.y;
    const int b = bh >> 4, h = bh & 15;
    const int tid = threadIdx.x;
    const int key = tid >> 2, c16 = (tid & 3) << 4;
    const unsigned short* kp = qkv16 + ((size_t)(b * 1024 + kc * 64 + key)) * 3072 + 1024 + h * 64 + c16;
    alignas(16) unsigned short kbuf[16];
    #pragma unroll
    for (int j = 0; j < 16; j += 8) {
        short8 k8 = *reinterpret_cast<const short8*>(kp + j);
        short8 v8 = *reinterpret_cast<const short8*>(kp + 1024 + j);
        #pragma unroll
        for (int c = 0; c < 8; ++c) {
            kbuf[j + c] = f2h(8.0f * h2f((unsigned short)k8[c]));
            VtT[c16 + j + c][key] = (unsigned short)v8[c];
        }
    }
    const size_t kb = ((size_t)bh * 1024 + kc * 64 + key) * 64 + c16;
    *reinterpret_cast<short8*>(K_g + kb)     = *reinterpret_cast<short8*>(&kbuf[0]);
    *reinterpret_cast<short8*>(K_g + kb + 8) = *reinterpret_cast<short8*>(&kbuf[8]);
    __syncthreads();
    const int d = tid >> 2;
    const size_t vb = ((size_t)bh * 64 + d) * 1024 + (size_t)kc * 64 + c16;
    *reinterpret_cast<short8*>(Vt_g + vb)     = *reinterpret_cast<const short8*>(&VtT[d][c16]);
    *reinterpret_cast<short8*>(Vt_g + vb + 8) = *reinterpret_cast<const short8*>(&VtT[d][c16 + 8]);
}

// ---------------- Flash attention (fp16, QBLK=64, T14 register prefetch) ----------------
__global__ __launch_bounds__(256)
void attn_kernel(const unsigned short* __restrict__ qkv16,
                 const unsigned short* __restrict__ K_g,
                 const unsigned short* __restrict__ Vt_g,
                 unsigned short* __restrict__ ctx) {
    __shared__ unsigned short Kh[64][72];
    __shared__ unsigned short Vt[64][72];
    __shared__ unsigned short Plds[4][16][72];
    const int qt = blockIdx.x;
    const int bh = blockIdx.y;
    const int b = bh >> 4, h = bh & 15;
    const int tid = threadIdx.x;
    const int wave = tid >> 6, lane = tid & 63;
    const int fr = lane & 15, g8 = (lane >> 4) << 3, fq = (lane >> 4) << 2;

    const int qrow = qt * 64 + wave * 16 + fr;
    const unsigned short* qp = qkv16 + ((size_t)(b * 1024 + qrow)) * 3072 + h * 64;
    half8 qf[2];
    qf[0] = *reinterpret_cast<const half8*>(qp + g8);
    qf[1] = *reinterpret_cast<const half8*>(qp + 32 + g8);

    float mrun[4], lrun[4];
    f32x4 cacc[4];
    #pragma unroll
    for (int r = 0; r < 4; ++r) { mrun[r] = -3.0e38f; lrun[r] = 0.0f; }
    #pragma unroll
    for (int nd = 0; nd < 4; ++nd)
        #pragma unroll
        for (int r = 0; r < 4; ++r) cacc[nd][r] = 0.0f;

    const int skey = tid >> 2, sc16 = (tid & 3) << 4;
    const unsigned short* kgp = K_g + ((size_t)bh * 1024 + skey) * 64 + sc16;
    const unsigned short* vgp = Vt_g + ((size_t)bh * 64 + skey) * 1024 + sc16;

    short8 ka = *reinterpret_cast<const short8*>(kgp);
    short8 kb = *reinterpret_cast<const short8*>(kgp + 8);
    short8 va = *reinterpret_cast<const short8*>(vgp);
    short8 vb = *reinterpret_cast<const short8*>(vgp + 8);

    for (int kt = 0; kt < 16; ++kt) {
        __syncthreads();
        *reinterpret_cast<short8*>(&Kh[skey][sc16])     = ka;
        *reinterpret_cast<short8*>(&Kh[skey][sc16 + 8]) = kb;
        *reinterpret_cast<short8*>(&Vt[skey][sc16])     = va;
        *reinterpret_cast<short8*>(&Vt[skey][sc16 + 8]) = vb;
        __syncthreads();
        const int ktn = (kt < 15) ? kt + 1 : 15;
        ka = *reinterpret_cast<const short8*>(kgp + (size_t)ktn * 4096);
        kb = *reinterpret_cast<const short8*>(kgp + (size_t)ktn * 4096 + 8);
        va = *reinterpret_cast<const short8*>(vgp + ktn * 64);
        vb = *reinterpret_cast<const short8*>(vgp + ktn * 64 + 8);

        f32x4 S[4];
        #pragma unroll
        for (int n = 0; n < 4; ++n)
            #pragma unroll
            for (int r = 0; r < 4; ++r) S[n][r] = 0.0f;
        #pragma unroll
        for (int s_ = 0; s_ < 2; ++s_)
            #pragma unroll
            for (int n = 0; n < 4; ++n) {
                half8 kh = *reinterpret_cast<const half8*>(&Kh[n * 16 + fr][s_ * 32 + g8]);
                S[n] = __builtin_amdgcn_mfma_f32_16x16x32_f16(qf[s_], kh, S[n], 0, 0, 0);
            }

        float mt[4];
        #pragma unroll
        for (int r = 0; r < 4; ++r)
            mt[r] = fmaxf(fmaxf(S[0][r], S[1][r]), fmaxf(S[2][r], S[3][r]));
        #pragma unroll
        for (int r = 0; r < 4; ++r) {
            mt[r] = fmaxf(mt[r], __shfl_xor(mt[r], 1));
            mt[r] = fmaxf(mt[r], __shfl_xor(mt[r], 2));
            mt[r] = fmaxf(mt[r], __shfl_xor(mt[r], 4));
            mt[r] = fmaxf(mt[r], __shfl_xor(mt[r], 8));
        }
        float P[4][4], rsum[4];
        #pragma unroll
        for (int r = 0; r < 4; ++r) {
            float mnew = fmaxf(mrun[r], mt[r]);
            float sf = __expf(mrun[r] - mnew);
            mrun[r] = mnew;
            rsum[r] = 0.0f;
            #pragma unroll
            for (int n = 0; n < 4; ++n) {
                float p = __expf(S[n][r] - mnew);
                P[n][r] = p;
                rsum[r] += p;
            }
            lrun[r] *= sf;
            #pragma unroll
            for (int nd = 0; nd < 4; ++nd) cacc[nd][r] *= sf;
        }
        #pragma unroll
        for (int r = 0; r < 4; ++r) {
            rsum[r] += __shfl_xor(rsum[r], 1);
            rsum[r] += __shfl_xor(rsum[r], 2);
            rsum[r] += __shfl_xor(rsum[r], 4);
            rsum[r] += __shfl_xor(rsum[r], 8);
            lrun[r] += rsum[r];
        }
        #pragma unroll
        for (int n = 0; n < 4; ++n)
            #pragma unroll
            for (int r = 0; r < 4; ++r)
                Plds[wave][fq + r][n * 16 + fr] = f2h(P[n][r]);
        #pragma unroll
        for (int s_ = 0; s_ < 2; ++s_) {
            half8 pa = *reinterpret_cast<const half8*>(&Plds[wave][fr][s_ * 32 + g8]);
            #pragma unroll
            for (int nd = 0; nd < 4; ++nd) {
                half8 vb8 = *reinterpret_cast<const half8*>(&Vt[nd * 16 + fr][s_ * 32 + g8]);
                cacc[nd] = __builtin_amdgcn_mfma_f32_16x16x32_f16(pa, vb8, cacc[nd], 0, 0, 0);
            }
        }
    }
    #pragma unroll
    for (int r = 0; r < 4; ++r) {
        const float inv = 1.0f / lrun[r];
        const int row = qt * 64 + wave * 16 + fq + r;
        unsigned short* cp = ctx + ((size_t)(b * 1024 + row)) * 1024 + h * 64;
        #pragma unroll
        for (int nd = 0; nd < 4; ++nd)
            cp[nd * 16 + fr] = f2h(cacc[nd][r] * inv);
    }
}

// ---------------- launch ----------------
extern "C" void kernel_launch(void* const* d_in, const int* in_sizes, int n_in,
                              void* d_out, int out_size, void* d_ws, size_t ws_size,
                              hipStream_t stream) {
    const float* x      = (const float*)d_in[0];
    const float* norm_g = (const float*)d_in[1];
    const float* norm_b = (const float*)d_in[2];
    const float* w_qkv  = (const float*)d_in[3];
    const float* b_qkv  = (const float*)d_in[4];
    const float* w_proj = (const float*)d_in[5];
    const float* b_proj = (const float*)d_in[6];
    const float* w_fc1  = (const float*)d_in[7];
    const float* b_fc1  = (const float*)d_in[8];
    const float* w_fc2  = (const float*)d_in[9];
    const float* b_fc2  = (const float*)d_in[10];
    float* out = (float*)d_out;
    char* ws = (char*)d_ws;

    size_t off = 0;
    unsigned short* wqkvT  = (unsigned short*)(ws + off); off += (size_t)3072 * 1024 * 2;
    unsigned short* wprojT = (unsigned short*)(ws + off); off += (size_t)1024 * 1024 * 2;
    unsigned short* wfc1T  = (unsigned short*)(ws + off); off += (size_t)4096 * 1024 * 2;
    unsigned short* wfc2T  = (unsigned short*)(ws + off); off += (size_t)1024 * 4096 * 2;
    unsigned short* ctxb   = (unsigned short*)(ws + off); off += (size_t)4096 * 1024 * 2;
    char* G = ws + off;
    // G region timeline (byte offsets; watermark identical to round 12):
    //   h1     ( 8.4 MB) at G+0         : ln -> qkv GEMM
    //   qkv16  (25.2 MB) at G+8388608   : qkv GEMM -> attn / kv_conv
    //   K_g    ( 8.4 MB) at G+0         : kv_conv -> attn (overlaps dead h1)
    //   Vt_g   ( 8.4 MB) at G+33554432  : kv_conv -> attn
    //   fc1o   (33.5 MB) at G+0         : fc1 -> fc2
    //   h2     ( 8.4 MB) at G+41943040  : ln2 -> fc1 (dead before fc2)
    //   fc2ph  [4][4096][1024] fp16 (33.5 MB) at G+33554432 : fc2 partials -> red
    unsigned short* h1    = (unsigned short*)G;
    unsigned short* qkv16 = (unsigned short*)(G + (size_t)8388608);
    unsigned short* K_g   = (unsigned short*)G;
    unsigned short* Vt_g  = (unsigned short*)(G + (size_t)33554432);
    unsigned short* fc1o  = (unsigned short*)G;
    unsigned short* h2    = (unsigned short*)(G + (size_t)41943040);
    unsigned short* fc2ph = (unsigned short*)(G + (size_t)33554432);

    // weight prep (fused single launch)
    transpose_all<<<12288, 256, 0, stream>>>(w_qkv, w_proj, w_fc1, w_fc2,
                                             wqkvT, wprojT, wfc1T, wfc2T);

    // h1 = LN(x) fp16 ; qkv16 = fp16(h1 @ w_qkv + b)   (gemm_mid: 384 blocks)
    ln_kernel<<<4096, 256, 0, stream>>>(x, norm_g, norm_b, h1);
    gemm_mid<0, 1><<<384, 512, 0, stream>>>(h1, wqkvT, b_qkv, qkv16,
                                            4096, 3072, 1024, 1024, 1024, 3072);

    // compact K (x8-scaled) and V^T
    kv_conv<<<dim3(16, 64), 256, 0, stream>>>(qkv16, K_g, Vt_g);

    // attention -> ctx (fp16), QBLK=64 (1024 blocks = 4/CU)
    attn_kernel<<<dim3(16, 64), 256, 0, stream>>>(qkv16, K_g, Vt_g, ctxb);

    // x1 = x + ctx @ w_proj + b  (2-phase BM=64 + XCD remap; x1 lives in d_out)
    gemm_bt<1, 64, 1><<<512, 256, 0, stream>>>(ctxb, wprojT, b_proj, x, out,
                                               4096, 1024, 1024, 1024, 1024, 1024);

    // h2 = LN(x1) ; fc1 = gelu(h2 @ w_fc1 + b)   (gemm_mid: 512 blocks = 2/CU)
    ln_kernel<<<4096, 256, 0, stream>>>(out, norm_g, norm_b, h2);
    gemm_mid<2, 1><<<512, 512, 0, stream>>>(h2, wfc1T, b_fc1, fc1o,
                                            4096, 4096, 1024, 1024, 1024, 4096);

    // fc2: gemm_mid split-K=4 (512 blocks = 2/CU), XCD-local A-tiles, fp16 partials
    gemm_mid<4, 4><<<512, 512, 0, stream>>>(fc1o, wfc2T, nullptr, fc2ph,
                                            4096, 1024, 1024, 4096, 4096, 1024);
    red_h<4><<<4096, 256, 0, stream>>>(fc2ph, b_fc2, out);
}

// Round 14
// 249.760 us; speedup vs baseline: 1.2214x; 1.0501x over previous
//
#include <hip/hip_runtime.h>
#include <hip/hip_bf16.h>

typedef __attribute__((ext_vector_type(8))) short short8;
typedef __attribute__((ext_vector_type(8))) _Float16 half8;
typedef __attribute__((ext_vector_type(4))) float f32x4;

__device__ __forceinline__ unsigned short f2h(float f) {
    _Float16 h = (_Float16)f;
    return *reinterpret_cast<unsigned short*>(&h);
}
__device__ __forceinline__ float h2f(unsigned short u) {
    _Float16 h = *reinterpret_cast<_Float16*>(&u);
    return (float)h;
}

// async global->LDS, 16B per lane, wave-uniform LDS base + lane*16 dest
__device__ __forceinline__ void gld_lds16(const unsigned short* g, unsigned short* l) {
    __builtin_amdgcn_global_load_lds(
        (const __attribute__((address_space(1))) unsigned int*)g,
        (__attribute__((address_space(3))) unsigned int*)l, 16, 0, 0);
}

// ---------------- fused weight transpose + fp16 convert (one launch) ----------------
__global__ __launch_bounds__(256)
void transpose_all(const float* __restrict__ W0, const float* __restrict__ W1,
                   const float* __restrict__ W2, const float* __restrict__ W3,
                   unsigned short* __restrict__ o0, unsigned short* __restrict__ o1,
                   unsigned short* __restrict__ o2, unsigned short* __restrict__ o3) {
    __shared__ float tile[32][33];
    const int bid = blockIdx.x;
    const float* W; unsigned short* out; int K, N, loc;
    if (bid < 3072)      { W = W0; out = o0; K = 1024; N = 3072; loc = bid; }
    else if (bid < 4096) { W = W1; out = o1; K = 1024; N = 1024; loc = bid - 3072; }
    else if (bid < 8192) { W = W2; out = o2; K = 1024; N = 4096; loc = bid - 4096; }
    else                 { W = W3; out = o3; K = 4096; N = 1024; loc = bid - 8192; }
    const int nx = N >> 5;
    const int n0 = (loc % nx) << 5, k0 = (loc / nx) << 5;
    const int tid = threadIdx.x;
    const int r = tid >> 3, c4 = (tid & 7) << 2;
    float4 v = *reinterpret_cast<const float4*>(W + (size_t)(k0 + r) * N + n0 + c4);
    tile[r][c4 + 0] = v.x; tile[r][c4 + 1] = v.y;
    tile[r][c4 + 2] = v.z; tile[r][c4 + 3] = v.w;
    __syncthreads();
    const int n = n0 + r;
    ushort4 o;
    o.x = f2h(tile[c4 + 0][r]); o.y = f2h(tile[c4 + 1][r]);
    o.z = f2h(tile[c4 + 2][r]); o.w = f2h(tile[c4 + 3][r]);
    *reinterpret_cast<ushort4*>(out + (size_t)n * K + k0 + c4) = o;
}

// ---------------- LayerNorm -> fp16 [row][1024] ----------------
__global__ __launch_bounds__(256)
void ln_kernel(const float* __restrict__ x, const float* __restrict__ gw,
               const float* __restrict__ bw, unsigned short* __restrict__ out) {
    const int row = blockIdx.x, tid = threadIdx.x;
    const float* xr = x + (size_t)row * 1024;
    float4 v = *reinterpret_cast<const float4*>(xr + tid * 4);
    float s = v.x + v.y + v.z + v.w;
    float sq = v.x * v.x + v.y * v.y + v.z * v.z + v.w * v.w;
    #pragma unroll
    for (int off = 1; off < 64; off <<= 1) {
        s  += __shfl_xor(s, off);
        sq += __shfl_xor(sq, off);
    }
    __shared__ float ps[4], pq[4];
    const int wave = tid >> 6;
    if ((tid & 63) == 0) { ps[wave] = s; pq[wave] = sq; }
    __syncthreads();
    s  = ps[0] + ps[1] + ps[2] + ps[3];
    sq = pq[0] + pq[1] + pq[2] + pq[3];
    const float mu = s * (1.0f / 1024.0f);
    const float var = sq * (1.0f / 1024.0f) - mu * mu;
    const float rs = rsqrtf(var + 1e-5f);
    float4 gv = *reinterpret_cast<const float4*>(gw + tid * 4);
    float4 bv = *reinterpret_cast<const float4*>(bw + tid * 4);
    ushort4 o;
    o.x = f2h((v.x - mu) * rs * gv.x + bv.x);
    o.y = f2h((v.y - mu) * rs * gv.y + bv.y);
    o.z = f2h((v.z - mu) * rs * gv.z + bv.z);
    o.w = f2h((v.w - mu) * rs * gv.w + bv.w);
    *reinterpret_cast<ushort4*>(out + (size_t)row * 1024 + tid * 4) = o;
}

// ---------------- mid-tile GEMM: 128x256, BK=32, 8 waves (2Mx4N), 48KB LDS ----------
// 2-phase prefetch; one barrier per K-tile; chunk-swizzled LDS (2-way conflicts, free).
// NZ==1: XCD swizzle = per-XCD contiguous bm stripes. NZ>1: xcd = bm%8, bn fastest.
// EPI 0: fp16 = acc+bias ; EPI 2: fp16 = gelu(acc+bias) ; EPI 4: fp16 raw partial
template<int EPI, int NZ>
__global__ __launch_bounds__(512, 4)
void gemm_mid(const unsigned short* __restrict__ A, const unsigned short* __restrict__ Bt,
              const float* __restrict__ bias, void* Cout,
              int M, int N, int K, int lda, int ldb, int ldc) {
    __shared__ unsigned short As[2][128 * 32];   // 8KB per buf
    __shared__ unsigned short Bs[2][256 * 32];   // 16KB per buf (total 48KB)
    const int tid = threadIdx.x;
    const int wave = tid >> 6, lane = tid & 63;
    const int nx = N >> 8;
    int bm, bn, z;
    if (NZ == 1) {
        const int nwg = gridDim.x;
        const int swz = (blockIdx.x & 7) * (nwg >> 3) + (blockIdx.x >> 3);
        bm = (swz / nx) << 7; bn = (swz % nx) << 8; z = 0;
    } else {
        int bid = blockIdx.x;
        const int xcd = bid & 7; int rest = bid >> 3;
        bn = (rest % nx) << 8; rest /= nx;
        z = rest % NZ; rest /= NZ;
        bm = (rest * 8 + xcd) << 7;              // requires (M/128) % 8 == 0
    }
    const size_t koff = (size_t)z * K;
    const int wm = wave >> 2, wn = wave & 3;     // 2 M-waves x 4 N-waves, 64x64 each
    const int fr = lane & 15, g8 = (lane >> 4) << 3, fq = (lane >> 4) << 2;
    const int jq = g8 >> 3;          // logical 16B chunk (0..3)
    const int sx2 = (fr >> 1) & 3;   // read-side XOR

    const int srow = lane >> 2;
    const int scol = ((lane & 3) ^ ((lane >> 3) & 3)) << 3;
    const unsigned short* gA  = A + (size_t)(bm + wave * 16 + srow) * lda + scol + koff;
    const unsigned short* gB0 = Bt + (size_t)(bn + wave * 32 + srow) * ldb + scol + koff;
    const unsigned short* gB1 = gB0 + (size_t)16 * ldb;
    const int lbA = wave * 512;      // wave-uniform LDS bases (shorts)
    const int lbB = wave * 1024;

    f32x4 acc[4][4];
    #pragma unroll
    for (int m = 0; m < 4; ++m)
        #pragma unroll
        for (int n_ = 0; n_ < 4; ++n_)
            #pragma unroll
            for (int r_ = 0; r_ < 4; ++r_) acc[m][n_][r_] = 0.0f;

    auto stage = [&](int buf, int k0) {
        gld_lds16(gA + k0, &As[buf][lbA]);
        gld_lds16(gB0 + k0, &Bs[buf][lbB]);
        gld_lds16(gB1 + k0, &Bs[buf][lbB + 512]);
    };
    auto compute = [&](int buf) {
        half8 af[4], bfv[4];
        #pragma unroll
        for (int m = 0; m < 4; ++m)
            af[m] = *reinterpret_cast<const half8*>(
                &As[buf][(wm * 64 + m * 16 + fr) * 32 + ((jq ^ sx2) << 3)]);
        #pragma unroll
        for (int n_ = 0; n_ < 4; ++n_)
            bfv[n_] = *reinterpret_cast<const half8*>(
                &Bs[buf][(wn * 64 + n_ * 16 + fr) * 32 + ((jq ^ sx2) << 3)]);
        #pragma unroll
        for (int m = 0; m < 4; ++m)
            #pragma unroll
            for (int n_ = 0; n_ < 4; ++n_)
                acc[m][n_] = __builtin_amdgcn_mfma_f32_16x16x32_f16(af[m], bfv[n_], acc[m][n_], 0, 0, 0);
    };

    const int nt = K >> 5;   // even for all our shapes
    stage(0, 0);
    __syncthreads();
    int k0 = 32;
    for (int t = 0; t < nt - 2; t += 2) {
        stage(1, k0);
        compute(0);
        __syncthreads();
        stage(0, k0 + 32);
        compute(1);
        __syncthreads();
        k0 += 64;
    }
    stage(1, k0);
    compute(0);
    __syncthreads();
    compute(1);

    if (EPI == 4) {
        unsigned short* P = reinterpret_cast<unsigned short*>(Cout) +
                            (size_t)z * (size_t)M * ldc;
        #pragma unroll
        for (int n_ = 0; n_ < 4; ++n_) {
            const int col = bn + wn * 64 + n_ * 16 + fr;
            #pragma unroll
            for (int m = 0; m < 4; ++m)
                #pragma unroll
                for (int r_ = 0; r_ < 4; ++r_) {
                    const int row = bm + wm * 64 + m * 16 + fq + r_;
                    P[(size_t)row * ldc + col] = f2h(acc[m][n_][r_]);
                }
        }
        return;
    }

    unsigned short* o16 = reinterpret_cast<unsigned short*>(Cout);
    #pragma unroll
    for (int n_ = 0; n_ < 4; ++n_) {
        const int col = bn + wn * 64 + n_ * 16 + fr;
        const float bc = bias[col];
        #pragma unroll
        for (int m = 0; m < 4; ++m) {
            #pragma unroll
            for (int r_ = 0; r_ < 4; ++r_) {
                const int row = bm + wm * 64 + m * 16 + fq + r_;
                const size_t idx = (size_t)row * ldc + col;
                float v = acc[m][n_][r_] + bc;
                if (EPI == 0) {
                    o16[idx] = f2h(v);
                } else {
                    float ge = 0.5f * v * (1.0f + erff(v * 0.70710678118654752f));
                    o16[idx] = f2h(ge);
                }
            }
        }
    }
}

// ---------------- 2-phase GEMM (skinny shapes), BK=32 chunk-swizzle -----------------
// REMAP=1: 1-D grid, xcd = bid&7 == bm%8, bn fastest within XCD.
// EPI 1: f32 = acc+bias+resid.
template<int EPI, int BM, int REMAP>
__global__ __launch_bounds__(256)
void gemm_bt(const unsigned short* __restrict__ A, const unsigned short* __restrict__ Bt,
             const float* __restrict__ bias, const float* resid,
             void* Cout, int M, int N, int K, int lda, int ldb, int ldc) {
    constexpr int MF = BM / 32;
    __shared__ unsigned short As[2][BM * 32];
    __shared__ unsigned short Bs[2][128 * 32];
    const int tid = threadIdx.x;
    const int wave = tid >> 6, lane = tid & 63;
    int bm, bn;
    if (REMAP) {
        const int nxr = N >> 7;
        int bid = blockIdx.x;
        const int xcd = bid & 7; int rest = bid >> 3;
        bn = (rest % nxr) << 7; rest /= nxr;
        bm = (rest * 8 + xcd) * BM;              // requires (M/BM) % 8 == 0
    } else {
        bm = blockIdx.y * BM; bn = blockIdx.x << 7;
    }
    const int wr = (wave >> 1) * (BM / 2), wc = (wave & 1) << 6;
    const int fr = lane & 15, g8 = (lane >> 4) << 3, fq = (lane >> 4) << 2;
    const int jq = g8 >> 3, sx2 = (fr >> 1) & 3;

    const int srowA = (BM == 128) ? ((wave << 5) + (lane >> 2)) : ((wave << 4) + (lane >> 2));
    const int srowB = (wave << 5) + (lane >> 2);
    const int scol = (((lane & 3) ^ ((lane >> 3) & 3))) << 3;
    const unsigned short* gA0 = A + (size_t)(bm + srowA) * lda + scol;
    const unsigned short* gA1 = gA0 + (size_t)16 * lda;      // BM==128 only
    const unsigned short* gB0 = Bt + (size_t)(bn + srowB) * ldb + scol;
    const unsigned short* gB1 = gB0 + (size_t)16 * ldb;

    f32x4 acc[MF][4];
    #pragma unroll
    for (int m = 0; m < MF; ++m)
        #pragma unroll
        for (int n = 0; n < 4; ++n)
            #pragma unroll
            for (int r = 0; r < 4; ++r) acc[m][n][r] = 0.0f;

    auto stage = [&](int buf, int k0) {
        unsigned short* lA = &As[buf][(BM == 128) ? (wave << 10) : (wave << 9)];
        unsigned short* lB = &Bs[buf][wave << 10];
        gld_lds16(gA0 + k0, lA);
        if constexpr (BM == 128) gld_lds16(gA1 + k0, lA + 512);
        gld_lds16(gB0 + k0, lB);
        gld_lds16(gB1 + k0, lB + 512);
    };
    auto compute = [&](int buf) {
        half8 af[MF], bfv[4];
        #pragma unroll
        for (int m = 0; m < MF; ++m)
            af[m] = *reinterpret_cast<const half8*>(
                &As[buf][(wr + m * 16 + fr) * 32 + ((jq ^ sx2) << 3)]);
        #pragma unroll
        for (int n = 0; n < 4; ++n)
            bfv[n] = *reinterpret_cast<const half8*>(
                &Bs[buf][(wc + n * 16 + fr) * 32 + ((jq ^ sx2) << 3)]);
        #pragma unroll
        for (int m = 0; m < MF; ++m)
            #pragma unroll
            for (int n = 0; n < 4; ++n)
                acc[m][n] = __builtin_amdgcn_mfma_f32_16x16x32_f16(af[m], bfv[n], acc[m][n], 0, 0, 0);
    };

    const int nt = K >> 5;
    stage(0, 0);
    __syncthreads();
    int k0 = 32;
    for (int t = 0; t < nt - 2; t += 2) {
        stage(1, k0);
        compute(0);
        __syncthreads();
        stage(0, k0 + 32);
        compute(1);
        __syncthreads();
        k0 += 64;
    }
    stage(1, k0);
    compute(0);
    __syncthreads();
    compute(1);

    #pragma unroll
    for (int n = 0; n < 4; ++n) {
        const int col = bn + wc + n * 16 + fr;
        const float bc = bias[col];
        #pragma unroll
        for (int m = 0; m < MF; ++m) {
            #pragma unroll
            for (int r = 0; r < 4; ++r) {
                const int row = bm + wr + m * 16 + fq + r;
                const size_t idx = (size_t)row * ldc + col;
                float v = acc[m][n][r] + bc;
                reinterpret_cast<float*>(Cout)[idx] = v + resid[idx];   // EPI 1
            }
        }
    }
}

// ---------------- split-K reduce (fp16 partials): out = out + bias + sum_z p[z] -----
template<int Z>
__global__ __launch_bounds__(256)
void red_h(const unsigned short* __restrict__ p, const float* __restrict__ bias,
           float* out) {
    const size_t MN = (size_t)4096 * 1024;
    const size_t i = ((size_t)blockIdx.x * 256 + threadIdx.x) * 4;
    float4 r  = *reinterpret_cast<const float4*>(out + i);
    float4 bb = *reinterpret_cast<const float4*>(bias + (i & 1023));
    float o0 = r.x + bb.x, o1 = r.y + bb.y, o2 = r.z + bb.z, o3 = r.w + bb.w;
    #pragma unroll
    for (int z = 0; z < Z; ++z) {
        ushort4 a = *reinterpret_cast<const ushort4*>(p + (size_t)z * MN + i);
        o0 += h2f(a.x); o1 += h2f(a.y); o2 += h2f(a.z); o3 += h2f(a.w);
    }
    float4 o; o.x = o0; o.y = o1; o.z = o2; o.w = o3;
    *reinterpret_cast<float4*>(out + i) = o;
}

// ---------------- K/V compaction ----------------
// K scaled by 8*log2(e): scores become S' = (q.k)*8*log2e, so softmax uses
// P = exp2(S' - m') -- mathematically identical to exp((q.k)*8 - m), one mul cheaper.
__global__ __launch_bounds__(256)
void kv_conv(const unsigned short* __restrict__ qkv16, unsigned short* __restrict__ K_g,
             unsigned short* __restrict__ Vt_g) {
    __shared__ unsigned short VtT[64][72];
    const int kc = blockIdx.x;
    const int bh = blockIdx.y;
    const int b = bh >> 4, h = bh & 15;
    const int tid = threadIdx.x;
    const int key = tid >> 2, c16 = (tid & 3) << 4;
    const unsigned short* kp = qkv16 + ((size_t)(b * 1024 + kc * 64 + key)) * 3072 + 1024 + h * 64 + c16;
    alignas(16) unsigned short kbuf[16];
    const float KSCALE = 8.0f * 1.44269504088896f;   // 8 * log2(e)
    #pragma unroll
    for (int j = 0; j < 16; j += 8) {
        short8 k8 = *reinterpret_cast<const short8*>(kp + j);
        short8 v8 = *reinterpret_cast<const short8*>(kp + 1024 + j);
        #pragma unroll
        for (int c = 0; c < 8; ++c) {
            kbuf[j + c] = f2h(KSCALE * h2f((unsigned short)k8[c]));
            VtT[c16 + j + c][key] = (unsigned short)v8[c];
        }
    }
    const size_t kb = ((size_t)bh * 1024 + kc * 64 + key) * 64 + c16;
    *reinterpret_cast<short8*>(K_g + kb)     = *reinterpret_cast<short8*>(&kbuf[0]);
    *reinterpret_cast<short8*>(K_g + kb + 8) = *reinterpret_cast<short8*>(&kbuf[8]);
    __syncthreads();
    const int d = tid >> 2;
    const size_t vb = ((size_t)bh * 64 + d) * 1024 + (size_t)kc * 64 + c16;
    *reinterpret_cast<short8*>(Vt_g + vb)     = *reinterpret_cast<const short8*>(&VtT[d][c16]);
    *reinterpret_cast<short8*>(Vt_g + vb + 8) = *reinterpret_cast<const short8*>(&VtT[d][c16 + 8]);
}

// ---------------- Flash attention (fp16, QBLK=64, exp2 + ones-MFMA + defer-max) -----
// grid: x = bh (64), y = qt (16) -> all qt-sharers of a head on ONE XCD (bh%8):
// per-XCD K/V working set 2MB < 4MB L2 (fixes 2.6x FETCH amplification).
// Softmax VALU diet: P = exp2(S - m) (log2e folded into K scale); row-sum lrun
// computed by an extra MFMA against a ones-fragment (rescales with cacc, all lanes
// end up holding it); rescale skipped unless max grew > 8 (defer-max, T13).
__global__ __launch_bounds__(256)
void attn_kernel(const unsigned short* __restrict__ qkv16,
                 const unsigned short* __restrict__ K_g,
                 const unsigned short* __restrict__ Vt_g,
                 unsigned short* __restrict__ ctx) {
    __shared__ unsigned short Kh[64][72];
    __shared__ unsigned short Vt[64][72];
    __shared__ unsigned short Plds[4][16][72];
    const int bh = blockIdx.x;          // head-major: co-XCD K/V sharing
    const int qt = blockIdx.y;
    const int b = bh >> 4, h = bh & 15;
    const int tid = threadIdx.x;
    const int wave = tid >> 6, lane = tid & 63;
    const int fr = lane & 15, g8 = (lane >> 4) << 3, fq = (lane >> 4) << 2;

    const int qrow = qt * 64 + wave * 16 + fr;
    const unsigned short* qp = qkv16 + ((size_t)(b * 1024 + qrow)) * 3072 + h * 64;
    half8 qf[2];
    qf[0] = *reinterpret_cast<const half8*>(qp + g8);
    qf[1] = *reinterpret_cast<const half8*>(qp + 32 + g8);

    half8 ones;
    #pragma unroll
    for (int j = 0; j < 8; ++j) ones[j] = (_Float16)1.0f;

    float mrun[4];
    f32x4 cacc[4], csum;
    #pragma unroll
    for (int r = 0; r < 4; ++r) { mrun[r] = -3.0e38f; csum[r] = 0.0f; }
    #pragma unroll
    for (int nd = 0; nd < 4; ++nd)
        #pragma unroll
        for (int r = 0; r < 4; ++r) cacc[nd][r] = 0.0f;

    const int skey = tid >> 2, sc16 = (tid & 3) << 4;
    const unsigned short* kgp = K_g + ((size_t)bh * 1024 + skey) * 64 + sc16;
    const unsigned short* vgp = Vt_g + ((size_t)bh * 64 + skey) * 1024 + sc16;

    short8 ka = *reinterpret_cast<const short8*>(kgp);
    short8 kb = *reinterpret_cast<const short8*>(kgp + 8);
    short8 va = *reinterpret_cast<const short8*>(vgp);
    short8 vb = *reinterpret_cast<const short8*>(vgp + 8);

    for (int kt = 0; kt < 16; ++kt) {
        __syncthreads();
        *reinterpret_cast<short8*>(&Kh[skey][sc16])     = ka;
        *reinterpret_cast<short8*>(&Kh[skey][sc16 + 8]) = kb;
        *reinterpret_cast<short8*>(&Vt[skey][sc16])     = va;
        *reinterpret_cast<short8*>(&Vt[skey][sc16 + 8]) = vb;
        __syncthreads();
        // T14: issue next tile's loads; hide under compute
        const int ktn = (kt < 15) ? kt + 1 : 15;
        ka = *reinterpret_cast<const short8*>(kgp + (size_t)ktn * 4096);
        kb = *reinterpret_cast<const short8*>(kgp + (size_t)ktn * 4096 + 8);
        va = *reinterpret_cast<const short8*>(vgp + ktn * 64);
        vb = *reinterpret_cast<const short8*>(vgp + ktn * 64 + 8);

        f32x4 S[4];
        #pragma unroll
        for (int n = 0; n < 4; ++n)
            #pragma unroll
            for (int r = 0; r < 4; ++r) S[n][r] = 0.0f;
        #pragma unroll
        for (int s_ = 0; s_ < 2; ++s_)
            #pragma unroll
            for (int n = 0; n < 4; ++n) {
                half8 kh = *reinterpret_cast<const half8*>(&Kh[n * 16 + fr][s_ * 32 + g8]);
                S[n] = __builtin_amdgcn_mfma_f32_16x16x32_f16(qf[s_], kh, S[n], 0, 0, 0);
            }

        // row max over 16 lanes (4 shuffle rounds)
        float mt[4];
        #pragma unroll
        for (int r = 0; r < 4; ++r)
            mt[r] = fmaxf(fmaxf(S[0][r], S[1][r]), fmaxf(S[2][r], S[3][r]));
        #pragma unroll
        for (int r = 0; r < 4; ++r) {
            mt[r] = fmaxf(mt[r], __shfl_xor(mt[r], 1));
            mt[r] = fmaxf(mt[r], __shfl_xor(mt[r], 2));
            mt[r] = fmaxf(mt[r], __shfl_xor(mt[r], 4));
            mt[r] = fmaxf(mt[r], __shfl_xor(mt[r], 8));
        }
        // defer-max: rescale only when any row max grew > 8 (wave-uniform)
        int grow = 0;
        #pragma unroll
        for (int r = 0; r < 4; ++r) grow |= (mt[r] > mrun[r] + 8.0f) ? 1 : 0;
        if (__any(grow)) {
            #pragma unroll
            for (int r = 0; r < 4; ++r) {
                float mnew = fmaxf(mrun[r], mt[r]);
                float sf = __builtin_amdgcn_exp2f(mrun[r] - mnew);
                mrun[r] = mnew;
                csum[r] *= sf;
                #pragma unroll
                for (int nd = 0; nd < 4; ++nd) cacc[nd][r] *= sf;
            }
        }
        // P = exp2(S - m), bounded by 2^8; write to per-wave LDS slab (same-wave RAW)
        #pragma unroll
        for (int r = 0; r < 4; ++r)
            #pragma unroll
            for (int n = 0; n < 4; ++n)
                Plds[wave][fq + r][n * 16 + fr] =
                    f2h(__builtin_amdgcn_exp2f(S[n][r] - mrun[r]));
        #pragma unroll
        for (int s_ = 0; s_ < 2; ++s_) {
            half8 pa = *reinterpret_cast<const half8*>(&Plds[wave][fr][s_ * 32 + g8]);
            #pragma unroll
            for (int nd = 0; nd < 4; ++nd) {
                half8 vb8 = *reinterpret_cast<const half8*>(&Vt[nd * 16 + fr][s_ * 32 + g8]);
                cacc[nd] = __builtin_amdgcn_mfma_f32_16x16x32_f16(pa, vb8, cacc[nd], 0, 0, 0);
            }
            csum = __builtin_amdgcn_mfma_f32_16x16x32_f16(pa, ones, csum, 0, 0, 0);
        }
    }
    // csum[r] = row-sum (identical across lanes' cols since all ones-cols equal)
    #pragma unroll
    for (int r = 0; r < 4; ++r) {
        const float inv = 1.0f / csum[r];
        const int row = qt * 64 + wave * 16 + fq + r;
        unsigned short* cp = ctx + ((size_t)(b * 1024 + row)) * 1024 + h * 64;
        #pragma unroll
        for (int nd = 0; nd < 4; ++nd)
            cp[nd * 16 + fr] = f2h(cacc[nd][r] * inv);
    }
}

// ---------------- launch ----------------
extern "C" void kernel_launch(void* const* d_in, const int* in_sizes, int n_in,
                              void* d_out, int out_size, void* d_ws, size_t ws_size,
                              hipStream_t stream) {
    const float* x      = (const float*)d_in[0];
    const float* norm_g = (const float*)d_in[1];
    const float* norm_b = (const float*)d_in[2];
    const float* w_qkv  = (const float*)d_in[3];
    const float* b_qkv  = (const float*)d_in[4];
    const float* w_proj = (const float*)d_in[5];
    const float* b_proj = (const float*)d_in[6];
    const float* w_fc1  = (const float*)d_in[7];
    const float* b_fc1  = (const float*)d_in[8];
    const float* w_fc2  = (const float*)d_in[9];
    const float* b_fc2  = (const float*)d_in[10];
    float* out = (float*)d_out;
    char* ws = (char*)d_ws;

    size_t off = 0;
    unsigned short* wqkvT  = (unsigned short*)(ws + off); off += (size_t)3072 * 1024 * 2;
    unsigned short* wprojT = (unsigned short*)(ws + off); off += (size_t)1024 * 1024 * 2;
    unsigned short* wfc1T  = (unsigned short*)(ws + off); off += (size_t)4096 * 1024 * 2;
    unsigned short* wfc2T  = (unsigned short*)(ws + off); off += (size_t)1024 * 4096 * 2;
    unsigned short* ctxb   = (unsigned short*)(ws + off); off += (size_t)4096 * 1024 * 2;
    char* G = ws + off;
    // G region timeline (byte offsets; watermark identical to rounds 12/13):
    //   h1     ( 8.4 MB) at G+0         : ln -> qkv GEMM
    //   qkv16  (25.2 MB) at G+8388608   : qkv GEMM -> attn / kv_conv
    //   K_g    ( 8.4 MB) at G+0         : kv_conv -> attn (overlaps dead h1)
    //   Vt_g   ( 8.4 MB) at G+33554432  : kv_conv -> attn
    //   fc1o   (33.5 MB) at G+0         : fc1 -> fc2
    //   h2     ( 8.4 MB) at G+41943040  : ln2 -> fc1 (dead before fc2)
    //   fc2ph  [4][4096][1024] fp16 (33.5 MB) at G+33554432 : fc2 partials -> red
    unsigned short* h1    = (unsigned short*)G;
    unsigned short* qkv16 = (unsigned short*)(G + (size_t)8388608);
    unsigned short* K_g   = (unsigned short*)G;
    unsigned short* Vt_g  = (unsigned short*)(G + (size_t)33554432);
    unsigned short* fc1o  = (unsigned short*)G;
    unsigned short* h2    = (unsigned short*)(G + (size_t)41943040);
    unsigned short* fc2ph = (unsigned short*)(G + (size_t)33554432);

    // weight prep (fused single launch)
    transpose_all<<<12288, 256, 0, stream>>>(w_qkv, w_proj, w_fc1, w_fc2,
                                             wqkvT, wprojT, wfc1T, wfc2T);

    // h1 = LN(x) fp16 ; qkv16 = fp16(h1 @ w_qkv + b)   (gemm_mid: 384 blocks)
    ln_kernel<<<4096, 256, 0, stream>>>(x, norm_g, norm_b, h1);
    gemm_mid<0, 1><<<384, 512, 0, stream>>>(h1, wqkvT, b_qkv, qkv16,
                                            4096, 3072, 1024, 1024, 1024, 3072);

    // compact K (x 8*log2e) and V^T
    kv_conv<<<dim3(16, 64), 256, 0, stream>>>(qkv16, K_g, Vt_g);

    // attention -> ctx (fp16); head-major grid for XCD-local K/V
    attn_kernel<<<dim3(64, 16), 256, 0, stream>>>(qkv16, K_g, Vt_g, ctxb);

    // x1 = x + ctx @ w_proj + b  (2-phase BM=64 + XCD remap; x1 lives in d_out)
    gemm_bt<1, 64, 1><<<512, 256, 0, stream>>>(ctxb, wprojT, b_proj, x, out,
                                               4096, 1024, 1024, 1024, 1024, 1024);

    // h2 = LN(x1) ; fc1 = gelu(h2 @ w_fc1 + b)   (gemm_mid: 512 blocks = 2/CU)
    ln_kernel<<<4096, 256, 0, stream>>>(out, norm_g, norm_b, h2);
    gemm_mid<2, 1><<<512, 512, 0, stream>>>(h2, wfc1T, b_fc1, fc1o,
                                            4096, 4096, 1024, 1024, 1024, 4096);

    // fc2: gemm_mid split-K=4 (512 blocks = 2/CU), XCD-local A-tiles, fp16 partials
    gemm_mid<4, 4><<<512, 512, 0, stream>>>(fc1o, wfc2T, nullptr, fc2ph,
                                            4096, 1024, 1024, 4096, 4096, 1024);
    red_h<4><<<4096, 256, 0, stream>>>(fc2ph, b_fc2, out);
}